// Round 5
// baseline (614.105 us; speedup 1.0000x reference)
//
#include <hip/hip_runtime.h>
#include <math.h>

#define NEG_SLOPE 0.2f
#define GAT_EPS 1e-16f

// ---- bf16 pair packing helpers (channel 2p in low half, 2p+1 in high) ----
__device__ __forceinline__ unsigned pack_bf16(float a, float b) {
    unsigned ua = __float_as_uint(a);
    unsigned ub = __float_as_uint(b);
    ua = (ua + 0x8000u) >> 16;          // round-to-nearest-ish
    ub = (ub + 0x8000u) & 0xffff0000u;
    return ua | ub;
}
__device__ __forceinline__ float bf_lo(unsigned pk) {
    return __uint_as_float(pk << 16);
}
__device__ __forceinline__ float bf_hi(unsigned pk) {
    return __uint_as_float(pk & 0xffff0000u);
}

// ===========================================================================
// CSR build, two-level binned (no global histogram, no global scatter):
//   k_bin:   edges -> 1563 coarse buckets (d>>6), payload = s | (d&63)<<24.
//            Appends cluster at bucket frontiers -> L2 lines fill -> no 16x
//            write amplification. Atomics on 1563 counters only.
//   k_bscan: single-block exclusive scan of bucket counts -> bucket bases.
//   k_csr:   block per bucket: LDS 64-bin histogram + LDS scan -> row_ptr
//            for its 64 nodes, then place edges into its <=8KB csr window
//            (L2-resident writes). LDS atomics only.
// Edge ids e >= E are self-loops (s = d = e - E). ei[0..E)=src, ei[E..2E)=dst.
// ===========================================================================
__global__ __launch_bounds__(256) void k_bin(
    const int* __restrict__ ei, int E, int N, int CAP,
    int* __restrict__ bcur, unsigned* __restrict__ slab)
{
    int Etot = E + N;
    int e = blockIdx.x * 256 + threadIdx.x;
    if (e >= Etot) return;
    int s, d;
    if (e < E) { s = ei[e]; d = ei[E + e]; }
    else       { s = e - E; d = s; }
    int b = d >> 6;
    unsigned w = (unsigned)s | ((unsigned)(d & 63) << 24);  // s < 2^24
    int pos = atomicAdd(&bcur[b], 1);
    if (pos < CAP) slab[(size_t)b * CAP + pos] = w;  // CAP=2048 vs mean ~1152: never drops
}

// Single block, 1024 threads, exclusive scan of up to 2048 bucket counts.
__global__ __launch_bounds__(1024) void k_bscan(
    const int* __restrict__ bcur, int* __restrict__ bbase, int NBK)
{
    __shared__ int sm[2048];
    int t = threadIdx.x;
    int c0 = (t < NBK) ? bcur[t] : 0;
    int c1 = (t + 1024 < NBK) ? bcur[t + 1024] : 0;
    sm[t] = c0; sm[t + 1024] = c1;
    __syncthreads();
    for (int off = 1; off < 2048; off <<= 1) {
        int v0 = (t >= off) ? sm[t - off] : 0;
        int v1 = (t + 1024 >= off) ? sm[t + 1024 - off] : 0;
        __syncthreads();
        sm[t] += v0; sm[t + 1024] += v1;
        __syncthreads();
    }
    if (t < NBK) bbase[t] = sm[t] - c0;
    if (t + 1024 < NBK) bbase[t + 1024] = sm[t + 1024] - c1;
}

__global__ __launch_bounds__(256) void k_csr(
    const int* __restrict__ bcur, const int* __restrict__ bbase,
    const unsigned* __restrict__ slab, int CAP,
    int* __restrict__ row_ptr, int* __restrict__ csr_src, int N, int Etot)
{
    __shared__ int sdeg[64];
    __shared__ int scur[64];
    int b = blockIdx.x;
    int tid = threadIdx.x;
    int count = min(bcur[b], CAP);
    int base = bbase[b];
    const unsigned* sl = slab + (size_t)b * CAP;

    if (tid < 64) sdeg[tid] = 0;
    __syncthreads();
    for (int i = tid; i < count; i += 256)
        atomicAdd(&sdeg[sl[i] >> 24], 1);
    __syncthreads();
    int mydeg = (tid < 64) ? sdeg[tid] : 0;
    for (int off = 1; off < 64; off <<= 1) {
        int add = (tid < 64 && tid >= off) ? sdeg[tid - off] : 0;
        __syncthreads();
        if (tid < 64) sdeg[tid] += add;
        __syncthreads();
    }
    if (tid < 64) {
        int excl = sdeg[tid] - mydeg;   // exclusive scan value
        scur[tid] = excl;
        int node = b * 64 + tid;
        if (node < N) row_ptr[node] = base + excl;
    }
    if (b == 0 && tid == 0) row_ptr[N] = Etot;
    __syncthreads();
    for (int i = tid; i < count; i += 256) {
        unsigned w = sl[i];
        int pos = base + atomicAdd(&scur[w >> 24], 1);
        csr_src[pos] = (int)(w & 0xFFFFFFu);
    }
}

// ===========================================================================
// xl1 = x @ W1 [N,64] -> packed bf16 pairs; as1/ad1 logits (f32).
// Thread per node; W1 (32 KB) in LDS; x read as float4.
// ===========================================================================
__global__ __launch_bounds__(256) void k_gemm1(
    const float* __restrict__ x, const float* __restrict__ W1,
    const float* __restrict__ a_src1, const float* __restrict__ a_dst1,
    unsigned* __restrict__ xl1b, float* __restrict__ as1,
    float* __restrict__ ad1, int N, int F)
{
    __shared__ float Ws[128 * 64];
    __shared__ float asrc[64];
    __shared__ float adst[64];
    for (int i = threadIdx.x; i < F * 64; i += 256) Ws[i] = W1[i];
    if (threadIdx.x < 64) {
        asrc[threadIdx.x] = a_src1[threadIdx.x];
        adst[threadIdx.x] = a_dst1[threadIdx.x];
    }
    __syncthreads();

    int n = blockIdx.x * 256 + threadIdx.x;
    if (n >= N) return;

    float acc[64];
#pragma unroll
    for (int c = 0; c < 64; c++) acc[c] = 0.0f;

    const float4* xr4 = (const float4*)(x + (size_t)n * F);
    for (int k4 = 0; k4 < F / 4; k4++) {
        float4 xv = xr4[k4];
        const float* w0 = &Ws[(k4 * 4 + 0) * 64];
        const float* w1 = &Ws[(k4 * 4 + 1) * 64];
        const float* w2 = &Ws[(k4 * 4 + 2) * 64];
        const float* w3 = &Ws[(k4 * 4 + 3) * 64];
#pragma unroll
        for (int c = 0; c < 64; c++) {
            float a = acc[c];
            a = fmaf(xv.x, w0[c], a);
            a = fmaf(xv.y, w1[c], a);
            a = fmaf(xv.z, w2[c], a);
            a = fmaf(xv.w, w3[c], a);
            acc[c] = a;
        }
    }

    unsigned* xo = xl1b + (size_t)n * 32;
#pragma unroll
    for (int p = 0; p < 32; p++) xo[p] = pack_bf16(acc[2 * p], acc[2 * p + 1]);

#pragma unroll
    for (int h = 0; h < 8; h++) {
        float s = 0.0f, t = 0.0f;
#pragma unroll
        for (int c = 0; c < 8; c++) {
            s = fmaf(acc[h * 8 + c], asrc[h * 8 + c], s);
            t = fmaf(acc[h * 8 + c], adst[h * 8 + c], t);
        }
        as1[(size_t)n * 8 + h] = s;
        ad1[(size_t)n * 8 + h] = t;
    }
}

// ===========================================================================
// Layer-1 aggregation (pull). Wave per dst. lane = 32*half + p;
// p = channel-pair (c=2p,2p+1), half-waves take even/odd edges, unroll x2
// -> 4 independent edge gathers in flight. shfl_xor(32) combines halves.
// Fused: normalize + b1 + ELU -> h1[d,64] f32.
// ===========================================================================
__global__ __launch_bounds__(256) void k_agg1(
    const int* __restrict__ row_ptr, const int* __restrict__ csr_src,
    const float* __restrict__ as1, const float* __restrict__ ad1,
    const unsigned* __restrict__ xl1b, const float* __restrict__ b1,
    float* __restrict__ h1, int N)
{
    int d = blockIdx.x * 4 + (threadIdx.x >> 6);
    int lane = threadIdx.x & 63;
    if (d >= N) return;
    int half = lane >> 5;
    int p = lane & 31;          // channel pair
    int h = p >> 2;             // head of channels 2p,2p+1

    int beg = row_ptr[d];
    int end = row_ptr[d + 1];
    float adh = ad1[(size_t)d * 8 + h];

    float ax0 = 0.f, ay0 = 0.f, dn0 = 0.f;
    float ax1 = 0.f, ay1 = 0.f, dn1 = 0.f;
    int i = beg + half;
    for (; i + 2 < end; i += 4) {
        int s0 = csr_src[i];
        int s1 = csr_src[i + 2];
        float al0 = as1[(size_t)s0 * 8 + h] + adh;
        float al1 = as1[(size_t)s1 * 8 + h] + adh;
        unsigned k0 = xl1b[(size_t)s0 * 32 + p];
        unsigned k1 = xl1b[(size_t)s1 * 32 + p];
        al0 = al0 > 0.f ? al0 : NEG_SLOPE * al0;
        al1 = al1 > 0.f ? al1 : NEG_SLOPE * al1;
        float e0 = __expf(al0);
        float e1 = __expf(al1);
        ax0 = fmaf(e0, bf_lo(k0), ax0); ay0 = fmaf(e0, bf_hi(k0), ay0); dn0 += e0;
        ax1 = fmaf(e1, bf_lo(k1), ax1); ay1 = fmaf(e1, bf_hi(k1), ay1); dn1 += e1;
    }
    if (i < end) {
        int s0 = csr_src[i];
        float al0 = as1[(size_t)s0 * 8 + h] + adh;
        unsigned k0 = xl1b[(size_t)s0 * 32 + p];
        al0 = al0 > 0.f ? al0 : NEG_SLOPE * al0;
        float e0 = __expf(al0);
        ax0 = fmaf(e0, bf_lo(k0), ax0); ay0 = fmaf(e0, bf_hi(k0), ay0); dn0 += e0;
    }

    float ax = ax0 + ax1, ay = ay0 + ay1, den = dn0 + dn1;
    ax += __shfl_xor(ax, 32);
    ay += __shfl_xor(ay, 32);
    den += __shfl_xor(den, 32);

    if (half == 0) {
        float inv = 1.0f / (den + GAT_EPS);
        float2 bv = ((const float2*)b1)[p];
        float hx = ax * inv + bv.x;
        float hy = ay * inv + bv.y;
        hx = hx > 0.f ? hx : expm1f(hx);
        hy = hy > 0.f ? hy : expm1f(hy);
        ((float2*)(h1 + (size_t)d * 64))[p] = make_float2(hx, hy);
    }
}

// ===========================================================================
// Layer-2 node transform: xl2 = h1 @ W2 [N,40] -> packed bf16; as2/ad2.
// Thread per node; W2 (64x40) in LDS.
// ===========================================================================
__global__ __launch_bounds__(256) void k_node2(
    const float* __restrict__ h1, const float* __restrict__ W2,
    const float* __restrict__ a_src2, const float* __restrict__ a_dst2,
    unsigned* __restrict__ xl2b, float* __restrict__ as2,
    float* __restrict__ ad2, int N)
{
    __shared__ float Ws[64 * 40];
    __shared__ float a2s[40];
    __shared__ float a2d[40];
    for (int i = threadIdx.x; i < 64 * 40; i += 256) Ws[i] = W2[i];
    if (threadIdx.x < 40) {
        a2s[threadIdx.x] = a_src2[threadIdx.x];
        a2d[threadIdx.x] = a_dst2[threadIdx.x];
    }
    __syncthreads();

    int n = blockIdx.x * 256 + threadIdx.x;
    if (n >= N) return;

    float o[40];
#pragma unroll
    for (int j = 0; j < 40; j++) o[j] = 0.0f;

    const float* hr = h1 + (size_t)n * 64;
    for (int k = 0; k < 64; k++) {
        float hk = hr[k];
#pragma unroll
        for (int j = 0; j < 40; j++) o[j] = fmaf(hk, Ws[k * 40 + j], o[j]);
    }

    float s = 0.0f, t = 0.0f;
    unsigned* xo = xl2b + (size_t)n * 20;
#pragma unroll
    for (int j = 0; j < 40; j++) {
        s = fmaf(o[j], a2s[j], s);
        t = fmaf(o[j], a2d[j], t);
    }
#pragma unroll
    for (int p = 0; p < 20; p++) xo[p] = pack_bf16(o[2 * p], o[2 * p + 1]);
    as2[n] = s;
    ad2[n] = t;
}

// ===========================================================================
// Layer-2 aggregation (pull). Wave per dst; pairs p=0..19 active for data,
// all lanes help with denominator of their half. Writes d_out directly.
// ===========================================================================
__global__ __launch_bounds__(256) void k_agg2(
    const int* __restrict__ row_ptr, const int* __restrict__ csr_src,
    const float* __restrict__ as2, const float* __restrict__ ad2,
    const unsigned* __restrict__ xl2b, const float* __restrict__ b2,
    float* __restrict__ out, int N)
{
    int d = blockIdx.x * 4 + (threadIdx.x >> 6);
    int lane = threadIdx.x & 63;
    if (d >= N) return;
    int half = lane >> 5;
    int p = lane & 31;          // channel pair, active if p<20

    int beg = row_ptr[d];
    int end = row_ptr[d + 1];
    float add = ad2[d];
    bool act = (p < 20);
    int pc = act ? p : 0;       // clamp so inactive lanes load a valid addr

    float ax0 = 0.f, ay0 = 0.f, dn0 = 0.f;
    float ax1 = 0.f, ay1 = 0.f, dn1 = 0.f;
    int i = beg + half;
    for (; i + 2 < end; i += 4) {
        int s0 = csr_src[i];
        int s1 = csr_src[i + 2];
        float al0 = as2[s0] + add;
        float al1 = as2[s1] + add;
        unsigned k0 = xl2b[(size_t)s0 * 20 + pc];
        unsigned k1 = xl2b[(size_t)s1 * 20 + pc];
        al0 = al0 > 0.f ? al0 : NEG_SLOPE * al0;
        al1 = al1 > 0.f ? al1 : NEG_SLOPE * al1;
        float e0 = __expf(al0);
        float e1 = __expf(al1);
        ax0 = fmaf(e0, bf_lo(k0), ax0); ay0 = fmaf(e0, bf_hi(k0), ay0); dn0 += e0;
        ax1 = fmaf(e1, bf_lo(k1), ax1); ay1 = fmaf(e1, bf_hi(k1), ay1); dn1 += e1;
    }
    if (i < end) {
        int s0 = csr_src[i];
        float al0 = as2[s0] + add;
        unsigned k0 = xl2b[(size_t)s0 * 20 + pc];
        al0 = al0 > 0.f ? al0 : NEG_SLOPE * al0;
        float e0 = __expf(al0);
        ax0 = fmaf(e0, bf_lo(k0), ax0); ay0 = fmaf(e0, bf_hi(k0), ay0); dn0 += e0;
    }

    float ax = ax0 + ax1, ay = ay0 + ay1, den = dn0 + dn1;
    ax += __shfl_xor(ax, 32);
    ay += __shfl_xor(ay, 32);
    den += __shfl_xor(den, 32);

    if (half == 0 && act) {
        float inv = 1.0f / (den + GAT_EPS);
        float2 bv = ((const float2*)b2)[p];
        ((float2*)(out + (size_t)d * 40))[p] =
            make_float2(ax * inv + bv.x, ay * inv + bv.y);
    }
}

extern "C" void kernel_launch(void* const* d_in, const int* in_sizes, int n_in,
                              void* d_out, int out_size, void* d_ws, size_t ws_size,
                              hipStream_t stream) {
    const float* x      = (const float*)d_in[0];
    const int*   ei     = (const int*)d_in[1];     // int32 on device
    const float* W1     = (const float*)d_in[2];
    const float* a_src1 = (const float*)d_in[3];
    const float* a_dst1 = (const float*)d_in[4];
    const float* b1     = (const float*)d_in[5];
    const float* W2     = (const float*)d_in[6];
    const float* a_src2 = (const float*)d_in[7];
    const float* a_dst2 = (const float*)d_in[8];
    const float* b2     = (const float*)d_in[9];

    int F = in_sizes[2] / 64;      // 128
    int N = in_sizes[0] / F;       // 100000
    int E = in_sizes[1] / 2;       // 1600000
    int Etot = E + N;
    int NBK = (N + 63) >> 6;       // 1563 coarse buckets (<=2048 for k_bscan)
    int CAP = 2048;                // mean bucket fill ~1152; 26-sigma margin

    // Workspace (4-byte words). Peak ~65 MB.
    unsigned* xl1b    = (unsigned*)d_ws;                   // N*32
    float*    h1      = (float*)(xl1b + (size_t)N * 32);   // N*64
    float*    as1     = h1 + (size_t)N * 64;               // N*8
    float*    ad1     = as1 + (size_t)N * 8;               // N*8
    int*      row_ptr = (int*)(ad1 + (size_t)N * 8);       // N+1
    int*      csr_src = row_ptr + (N + 1);                 // Etot
    int*      bcur    = csr_src + Etot;                    // NBK
    int*      bbase   = bcur + NBK;                        // NBK
    unsigned* slab    = (unsigned*)(bbase + NBK);          // NBK*CAP
    // Aliases (live only after k_agg1; originals dead by then):
    unsigned* xl2b    = xl1b;                              // N*20 <= N*32
    float*    as2     = as1;                               // N
    float*    ad2     = ad1;                               // N

    // ---- CSR build (two-level binned; shared by both layers) ----
    hipMemsetAsync(bcur, 0, (size_t)NBK * sizeof(int), stream);
    k_bin  <<<(Etot + 255) / 256, 256, 0, stream>>>(ei, E, N, CAP, bcur, slab);
    k_bscan<<<1, 1024, 0, stream>>>(bcur, bbase, NBK);
    k_csr  <<<NBK, 256, 0, stream>>>(bcur, bbase, slab, CAP,
                                     row_ptr, csr_src, N, Etot);

    // ---- Layer 1 ----
    k_gemm1<<<(N + 255) / 256, 256, 0, stream>>>(x, W1, a_src1, a_dst1,
                                                 xl1b, as1, ad1, N, F);
    k_agg1 <<<(N + 3) / 4, 256, 0, stream>>>(row_ptr, csr_src, as1, ad1,
                                             xl1b, b1, h1, N);

    // ---- Layer 2 ----
    k_node2<<<(N + 255) / 256, 256, 0, stream>>>(h1, W2, a_src2, a_dst2,
                                                 xl2b, as2, ad2, N);
    k_agg2 <<<(N + 3) / 4, 256, 0, stream>>>(row_ptr, csr_src, as2, ad2,
                                             xl2b, b2, (float*)d_out, N);
}

// Round 6
// 447.318 us; speedup vs baseline: 1.3729x; 1.3729x over previous
//
#include <hip/hip_runtime.h>
#include <math.h>

#define NEG_SLOPE 0.2f
#define GAT_EPS 1e-16f

#define CH   8192   // edges per chunk (k_cnt / k_place)
#define NBK  256    // coarse buckets; bucket = d >> SHIFT (512 nodes/bucket)
// Pack constraint: s < 2^17 (N <= 131072) and (d & 511) in bits 17..25.

// ---- bf16 pair packing helpers (channel 2p in low half, 2p+1 in high) ----
__device__ __forceinline__ unsigned pack_bf16(float a, float b) {
    unsigned ua = __float_as_uint(a);
    unsigned ub = __float_as_uint(b);
    ua = (ua + 0x8000u) >> 16;
    ub = (ub + 0x8000u) & 0xffff0000u;
    return ua | ub;
}
__device__ __forceinline__ float bf_lo(unsigned pk) {
    return __uint_as_float(pk << 16);
}
__device__ __forceinline__ float bf_hi(unsigned pk) {
    return __uint_as_float(pk & 0xffff0000u);
}

// ===========================================================================
// CSR build via deterministic two-level counting sort — ZERO global atomics.
// Edge ids e >= E are self-loops (s = d = e - E). ei[0..E)=src, ei[E..2E)=dst.
// ===========================================================================

// Pass A: per-chunk LDS histogram over coarse buckets -> cnt[chunk][NBK].
__global__ __launch_bounds__(256) void k_cnt(
    const int* __restrict__ ei, int E, int N, int shift,
    int* __restrict__ cnt)
{
    __shared__ int h[NBK];
    int c = blockIdx.x;
    h[threadIdx.x] = 0;
    __syncthreads();
    int Etot = E + N;
    int base = c * CH;
    int lim = min(base + CH, Etot);
    for (int e = base + threadIdx.x; e < lim; e += 256) {
        int d = (e < E) ? ei[E + e] : (e - E);
        atomicAdd(&h[d >> shift], 1);
    }
    __syncthreads();
    cnt[c * NBK + threadIdx.x] = h[threadIdx.x];
}

// Pass B: column-wise running sums + bucket-base scan -> off[chunk][NBK],
// bbase[NBK+1]. Single block, 256 threads (thread = bucket).
__global__ __launch_bounds__(256) void k_off(
    const int* __restrict__ cnt, int* __restrict__ off,
    int* __restrict__ bbase, int NCH)
{
    __shared__ int tot[NBK];
    int b = threadIdx.x;
    int run = 0;
    for (int c = 0; c < NCH; c++) {
        off[c * NBK + b] = run;
        run += cnt[c * NBK + b];
    }
    tot[b] = run;
    __syncthreads();
    int v0 = tot[b];
    for (int o = 1; o < NBK; o <<= 1) {
        int v = (b >= o) ? tot[b - o] : 0;
        __syncthreads();
        tot[b] += v;
        __syncthreads();
    }
    int excl = tot[b] - v0;
    bbase[b] = excl;
    if (b == NBK - 1) bbase[NBK] = excl + v0;
    for (int c = 0; c < NCH; c++) off[c * NBK + b] += excl;
}

// Pass C: re-read chunk edges, rank via LDS cursors (init from off), write
// packed (s | (d&mask)<<17) into the chunk's exclusive slab ranges.
__global__ __launch_bounds__(256) void k_place(
    const int* __restrict__ ei, int E, int N, int shift,
    const int* __restrict__ off, unsigned* __restrict__ bslab)
{
    __shared__ int cur[NBK];
    int c = blockIdx.x;
    cur[threadIdx.x] = off[c * NBK + threadIdx.x];
    __syncthreads();
    int Etot = E + N;
    int base = c * CH;
    int lim = min(base + CH, Etot);
    int mask = (1 << shift) - 1;
    for (int e = base + threadIdx.x; e < lim; e += 256) {
        int s, d;
        if (e < E) { s = ei[e]; d = ei[E + e]; }
        else       { s = e - E; d = s; }
        int b = d >> shift;
        int pos = atomicAdd(&cur[b], 1);  // LDS atomic
        bslab[pos] = (unsigned)s | ((unsigned)(d & mask) << 17);
    }
}

// Pass D: block per bucket: LDS fine histogram + scan -> row_ptr, then place
// srcs into the bucket's csr_src window (L2-local). LDS atomics only.
__global__ __launch_bounds__(256) void k_csr2(
    const int* __restrict__ bbase, const unsigned* __restrict__ bslab,
    int shift, int* __restrict__ row_ptr, int* __restrict__ csr_src,
    int N, int Etot)
{
    __shared__ int sdeg[1024];
    __shared__ int scur[1024];
    __shared__ int ps[256];
    int b = blockIdx.x;
    int tid = threadIdx.x;
    int beg = bbase[b], end = bbase[b + 1];
    int nodes = 1 << shift;            // 512 (shift=9); LDS sized for <=1024
    int node0 = b << shift;
    for (int i = tid; i < nodes; i += 256) sdeg[i] = 0;
    __syncthreads();
    for (int i = beg + tid; i < end; i += 256)
        atomicAdd(&sdeg[bslab[i] >> 17], 1);
    __syncthreads();
    // exclusive scan over 'nodes' bins: per-thread chunk + 256-wide scan
    int per = (nodes + 255) / 256;
    int mybase = tid * per;
    int sum = 0;
    for (int j = 0; j < per; j++) sum += sdeg[mybase + j];
    ps[tid] = sum;
    __syncthreads();
    int v0 = ps[tid];
    for (int o = 1; o < 256; o <<= 1) {
        int v = (tid >= o) ? ps[tid - o] : 0;
        __syncthreads();
        ps[tid] += v;
        __syncthreads();
    }
    int run = ps[tid] - v0;
    for (int j = 0; j < per; j++) {
        int i = mybase + j;
        int dgi = sdeg[i];
        scur[i] = beg + run;
        int node = node0 + i;
        if (node < N) row_ptr[node] = beg + run;
        run += dgi;
    }
    if (b == 0 && tid == 0) row_ptr[N] = Etot;
    __syncthreads();
    for (int i = beg + tid; i < end; i += 256) {
        unsigned w = bslab[i];
        int pos = atomicAdd(&scur[w >> 17], 1);  // LDS atomic
        csr_src[pos] = (int)(w & 0x1FFFFu);
    }
}

// ===========================================================================
// xl1 = x @ W1 [N,64] -> packed bf16 pairs; as1/ad1 logits (f32).
// Thread per node; W1 (32 KB) in LDS; x read as float4.
// ===========================================================================
__global__ __launch_bounds__(256) void k_gemm1(
    const float* __restrict__ x, const float* __restrict__ W1,
    const float* __restrict__ a_src1, const float* __restrict__ a_dst1,
    unsigned* __restrict__ xl1b, float* __restrict__ as1,
    float* __restrict__ ad1, int N, int F)
{
    __shared__ float Ws[128 * 64];
    __shared__ float asrc[64];
    __shared__ float adst[64];
    for (int i = threadIdx.x; i < F * 64; i += 256) Ws[i] = W1[i];
    if (threadIdx.x < 64) {
        asrc[threadIdx.x] = a_src1[threadIdx.x];
        adst[threadIdx.x] = a_dst1[threadIdx.x];
    }
    __syncthreads();

    int n = blockIdx.x * 256 + threadIdx.x;
    if (n >= N) return;

    float acc[64];
#pragma unroll
    for (int c = 0; c < 64; c++) acc[c] = 0.0f;

    const float4* xr4 = (const float4*)(x + (size_t)n * F);
    for (int k4 = 0; k4 < F / 4; k4++) {
        float4 xv = xr4[k4];
        const float* w0 = &Ws[(k4 * 4 + 0) * 64];
        const float* w1 = &Ws[(k4 * 4 + 1) * 64];
        const float* w2 = &Ws[(k4 * 4 + 2) * 64];
        const float* w3 = &Ws[(k4 * 4 + 3) * 64];
#pragma unroll
        for (int c = 0; c < 64; c++) {
            float a = acc[c];
            a = fmaf(xv.x, w0[c], a);
            a = fmaf(xv.y, w1[c], a);
            a = fmaf(xv.z, w2[c], a);
            a = fmaf(xv.w, w3[c], a);
            acc[c] = a;
        }
    }

    unsigned* xo = xl1b + (size_t)n * 32;
#pragma unroll
    for (int p = 0; p < 32; p++) xo[p] = pack_bf16(acc[2 * p], acc[2 * p + 1]);

#pragma unroll
    for (int h = 0; h < 8; h++) {
        float s = 0.0f, t = 0.0f;
#pragma unroll
        for (int c = 0; c < 8; c++) {
            s = fmaf(acc[h * 8 + c], asrc[h * 8 + c], s);
            t = fmaf(acc[h * 8 + c], adst[h * 8 + c], t);
        }
        as1[(size_t)n * 8 + h] = s;
        ad1[(size_t)n * 8 + h] = t;
    }
}

// ===========================================================================
// Layer-1 aggregation (pull). Wave per dst. lane = 32*half + p;
// half-waves take even/odd edges, unroll x2 -> 4 gathers in flight.
// Fused: normalize + b1 + ELU -> h1[d,64] f32.
// ===========================================================================
__global__ __launch_bounds__(256) void k_agg1(
    const int* __restrict__ row_ptr, const int* __restrict__ csr_src,
    const float* __restrict__ as1, const float* __restrict__ ad1,
    const unsigned* __restrict__ xl1b, const float* __restrict__ b1,
    float* __restrict__ h1, int N)
{
    int d = blockIdx.x * 4 + (threadIdx.x >> 6);
    int lane = threadIdx.x & 63;
    if (d >= N) return;
    int half = lane >> 5;
    int p = lane & 31;          // channel pair
    int h = p >> 2;             // head of channels 2p,2p+1

    int beg = row_ptr[d];
    int end = row_ptr[d + 1];
    float adh = ad1[(size_t)d * 8 + h];

    float ax0 = 0.f, ay0 = 0.f, dn0 = 0.f;
    float ax1 = 0.f, ay1 = 0.f, dn1 = 0.f;
    int i = beg + half;
    for (; i + 2 < end; i += 4) {
        int s0 = csr_src[i];
        int s1 = csr_src[i + 2];
        float al0 = as1[(size_t)s0 * 8 + h] + adh;
        float al1 = as1[(size_t)s1 * 8 + h] + adh;
        unsigned k0 = xl1b[(size_t)s0 * 32 + p];
        unsigned k1 = xl1b[(size_t)s1 * 32 + p];
        al0 = al0 > 0.f ? al0 : NEG_SLOPE * al0;
        al1 = al1 > 0.f ? al1 : NEG_SLOPE * al1;
        float e0 = __expf(al0);
        float e1 = __expf(al1);
        ax0 = fmaf(e0, bf_lo(k0), ax0); ay0 = fmaf(e0, bf_hi(k0), ay0); dn0 += e0;
        ax1 = fmaf(e1, bf_lo(k1), ax1); ay1 = fmaf(e1, bf_hi(k1), ay1); dn1 += e1;
    }
    if (i < end) {
        int s0 = csr_src[i];
        float al0 = as1[(size_t)s0 * 8 + h] + adh;
        unsigned k0 = xl1b[(size_t)s0 * 32 + p];
        al0 = al0 > 0.f ? al0 : NEG_SLOPE * al0;
        float e0 = __expf(al0);
        ax0 = fmaf(e0, bf_lo(k0), ax0); ay0 = fmaf(e0, bf_hi(k0), ay0); dn0 += e0;
    }

    float ax = ax0 + ax1, ay = ay0 + ay1, den = dn0 + dn1;
    ax += __shfl_xor(ax, 32);
    ay += __shfl_xor(ay, 32);
    den += __shfl_xor(den, 32);

    if (half == 0) {
        float inv = 1.0f / (den + GAT_EPS);
        float2 bv = ((const float2*)b1)[p];
        float hx = ax * inv + bv.x;
        float hy = ay * inv + bv.y;
        hx = hx > 0.f ? hx : expm1f(hx);
        hy = hy > 0.f ? hy : expm1f(hy);
        ((float2*)(h1 + (size_t)d * 64))[p] = make_float2(hx, hy);
    }
}

// ===========================================================================
// Layer-2 node transform: xl2 = h1 @ W2 [N,40] -> packed bf16; as2/ad2.
// ===========================================================================
__global__ __launch_bounds__(256) void k_node2(
    const float* __restrict__ h1, const float* __restrict__ W2,
    const float* __restrict__ a_src2, const float* __restrict__ a_dst2,
    unsigned* __restrict__ xl2b, float* __restrict__ as2,
    float* __restrict__ ad2, int N)
{
    __shared__ float Ws[64 * 40];
    __shared__ float a2s[40];
    __shared__ float a2d[40];
    for (int i = threadIdx.x; i < 64 * 40; i += 256) Ws[i] = W2[i];
    if (threadIdx.x < 40) {
        a2s[threadIdx.x] = a_src2[threadIdx.x];
        a2d[threadIdx.x] = a_dst2[threadIdx.x];
    }
    __syncthreads();

    int n = blockIdx.x * 256 + threadIdx.x;
    if (n >= N) return;

    float o[40];
#pragma unroll
    for (int j = 0; j < 40; j++) o[j] = 0.0f;

    const float* hr = h1 + (size_t)n * 64;
    for (int k = 0; k < 64; k++) {
        float hk = hr[k];
#pragma unroll
        for (int j = 0; j < 40; j++) o[j] = fmaf(hk, Ws[k * 40 + j], o[j]);
    }

    float s = 0.0f, t = 0.0f;
    unsigned* xo = xl2b + (size_t)n * 20;
#pragma unroll
    for (int j = 0; j < 40; j++) {
        s = fmaf(o[j], a2s[j], s);
        t = fmaf(o[j], a2d[j], t);
    }
#pragma unroll
    for (int p = 0; p < 20; p++) xo[p] = pack_bf16(o[2 * p], o[2 * p + 1]);
    as2[n] = s;
    ad2[n] = t;
}

// ===========================================================================
// Layer-2 aggregation (pull). Wave per dst; pairs p=0..19 active for data.
// Writes d_out directly.
// ===========================================================================
__global__ __launch_bounds__(256) void k_agg2(
    const int* __restrict__ row_ptr, const int* __restrict__ csr_src,
    const float* __restrict__ as2, const float* __restrict__ ad2,
    const unsigned* __restrict__ xl2b, const float* __restrict__ b2,
    float* __restrict__ out, int N)
{
    int d = blockIdx.x * 4 + (threadIdx.x >> 6);
    int lane = threadIdx.x & 63;
    if (d >= N) return;
    int half = lane >> 5;
    int p = lane & 31;          // channel pair, active if p<20

    int beg = row_ptr[d];
    int end = row_ptr[d + 1];
    float add = ad2[d];
    bool act = (p < 20);
    int pc = act ? p : 0;

    float ax0 = 0.f, ay0 = 0.f, dn0 = 0.f;
    float ax1 = 0.f, ay1 = 0.f, dn1 = 0.f;
    int i = beg + half;
    for (; i + 2 < end; i += 4) {
        int s0 = csr_src[i];
        int s1 = csr_src[i + 2];
        float al0 = as2[s0] + add;
        float al1 = as2[s1] + add;
        unsigned k0 = xl2b[(size_t)s0 * 20 + pc];
        unsigned k1 = xl2b[(size_t)s1 * 20 + pc];
        al0 = al0 > 0.f ? al0 : NEG_SLOPE * al0;
        al1 = al1 > 0.f ? al1 : NEG_SLOPE * al1;
        float e0 = __expf(al0);
        float e1 = __expf(al1);
        ax0 = fmaf(e0, bf_lo(k0), ax0); ay0 = fmaf(e0, bf_hi(k0), ay0); dn0 += e0;
        ax1 = fmaf(e1, bf_lo(k1), ax1); ay1 = fmaf(e1, bf_hi(k1), ay1); dn1 += e1;
    }
    if (i < end) {
        int s0 = csr_src[i];
        float al0 = as2[s0] + add;
        unsigned k0 = xl2b[(size_t)s0 * 20 + pc];
        al0 = al0 > 0.f ? al0 : NEG_SLOPE * al0;
        float e0 = __expf(al0);
        ax0 = fmaf(e0, bf_lo(k0), ax0); ay0 = fmaf(e0, bf_hi(k0), ay0); dn0 += e0;
    }

    float ax = ax0 + ax1, ay = ay0 + ay1, den = dn0 + dn1;
    ax += __shfl_xor(ax, 32);
    ay += __shfl_xor(ay, 32);
    den += __shfl_xor(den, 32);

    if (half == 0 && act) {
        float inv = 1.0f / (den + GAT_EPS);
        float2 bv = ((const float2*)b2)[p];
        ((float2*)(out + (size_t)d * 40))[p] =
            make_float2(ax * inv + bv.x, ay * inv + bv.y);
    }
}

extern "C" void kernel_launch(void* const* d_in, const int* in_sizes, int n_in,
                              void* d_out, int out_size, void* d_ws, size_t ws_size,
                              hipStream_t stream) {
    const float* x      = (const float*)d_in[0];
    const int*   ei     = (const int*)d_in[1];     // int32 on device
    const float* W1     = (const float*)d_in[2];
    const float* a_src1 = (const float*)d_in[3];
    const float* a_dst1 = (const float*)d_in[4];
    const float* b1     = (const float*)d_in[5];
    const float* W2     = (const float*)d_in[6];
    const float* a_src2 = (const float*)d_in[7];
    const float* a_dst2 = (const float*)d_in[8];
    const float* b2     = (const float*)d_in[9];

    int F = in_sizes[2] / 64;      // 128
    int N = in_sizes[0] / F;       // 100000
    int E = in_sizes[1] / 2;       // 1600000
    int Etot = E + N;
    int NCH = (Etot + CH - 1) / CH;  // 208 chunks
    int shift = 9;                   // 512 nodes/bucket; N<131072 -> <=196 buckets
    while (((N - 1) >> shift) >= NBK) shift++;  // safety (LDS supports shift<=10)

    // Workspace (4-byte words). Peak ~59 MB.
    unsigned* xl1b    = (unsigned*)d_ws;                   // N*32
    float*    h1      = (float*)(xl1b + (size_t)N * 32);   // N*64
    float*    as1     = h1 + (size_t)N * 64;               // N*8
    float*    ad1     = as1 + (size_t)N * 8;               // N*8
    int*      row_ptr = (int*)(ad1 + (size_t)N * 8);       // N+1
    int*      csr_src = row_ptr + (N + 1);                 // Etot
    int*      cnt     = csr_src + Etot;                    // NCH*NBK
    int*      off     = cnt + (size_t)NCH * NBK;           // NCH*NBK
    int*      bbase   = off + (size_t)NCH * NBK;           // NBK+1
    unsigned* bslab   = (unsigned*)(bbase + NBK + 1);      // Etot
    // Aliases (live only after k_agg1; originals dead by then):
    unsigned* xl2b    = xl1b;                              // N*20 <= N*32
    float*    as2     = as1;                               // N
    float*    ad2     = ad1;                               // N

    // ---- CSR build: deterministic counting sort, zero global atomics ----
    k_cnt  <<<NCH, 256, 0, stream>>>(ei, E, N, shift, cnt);
    k_off  <<<1, 256, 0, stream>>>(cnt, off, bbase, NCH);
    k_place<<<NCH, 256, 0, stream>>>(ei, E, N, shift, off, bslab);
    k_csr2 <<<NBK, 256, 0, stream>>>(bbase, bslab, shift,
                                     row_ptr, csr_src, N, Etot);

    // ---- Layer 1 ----
    k_gemm1<<<(N + 255) / 256, 256, 0, stream>>>(x, W1, a_src1, a_dst1,
                                                 xl1b, as1, ad1, N, F);
    k_agg1 <<<(N + 3) / 4, 256, 0, stream>>>(row_ptr, csr_src, as1, ad1,
                                             xl1b, b1, h1, N);

    // ---- Layer 2 ----
    k_node2<<<(N + 255) / 256, 256, 0, stream>>>(h1, W2, a_src2, a_dst2,
                                                 xl2b, as2, ad2, N);
    k_agg2 <<<(N + 3) / 4, 256, 0, stream>>>(row_ptr, csr_src, as2, ad2,
                                             xl2b, b2, (float*)d_out, N);
}

// Round 7
// 373.342 us; speedup vs baseline: 1.6449x; 1.1981x over previous
//
#include <hip/hip_runtime.h>
#include <math.h>

#define NEG_SLOPE 0.2f
#define GAT_EPS 1e-16f

#define CH   8192   // edges per chunk (k_cnt / k_place)
#define NBK  256    // coarse buckets; bucket = d >> SHIFT (512 nodes/bucket)
// Pack constraint: s < 2^17 (N <= 131072) and (d & 511) in bits 17..25.

// ---- bf16 pair packing helpers (channel 2p in low half, 2p+1 in high) ----
__device__ __forceinline__ unsigned pack_bf16(float a, float b) {
    unsigned ua = __float_as_uint(a);
    unsigned ub = __float_as_uint(b);
    ua = (ua + 0x8000u) >> 16;
    ub = (ub + 0x8000u) & 0xffff0000u;
    return ua | ub;
}
__device__ __forceinline__ float bf_lo(unsigned pk) {
    return __uint_as_float(pk << 16);
}
__device__ __forceinline__ float bf_hi(unsigned pk) {
    return __uint_as_float(pk & 0xffff0000u);
}

// ===========================================================================
// CSR build via deterministic two-level counting sort — ZERO global atomics.
// Edge ids e >= E are self-loops (s = d = e - E). ei[0..E)=src, ei[E..2E)=dst.
// ===========================================================================

// Pass A: per-chunk LDS histogram over coarse buckets -> cnt[chunk][NBK].
__global__ __launch_bounds__(256) void k_cnt(
    const int* __restrict__ ei, int E, int N, int shift,
    int* __restrict__ cnt)
{
    __shared__ int h[NBK];
    int c = blockIdx.x;
    h[threadIdx.x] = 0;
    __syncthreads();
    int Etot = E + N;
    int base = c * CH;
    int lim = min(base + CH, Etot);
    for (int e = base + threadIdx.x; e < lim; e += 256) {
        int d = (e < E) ? ei[E + e] : (e - E);
        atomicAdd(&h[d >> shift], 1);
    }
    __syncthreads();
    cnt[c * NBK + threadIdx.x] = h[threadIdx.x];
}

// Pass B1: PARALLEL per-bucket scan over chunks. Block b: threads load
// cnt[c][b] for all c, LDS scan -> off[c][b] (bucket-local exclusive
// prefix), and tot[b] = bucket total. (Replaces the serial single-block
// k_off that was 80 us / top dispatch: 0.04% occupancy, dependent L2
// round-trips. 256 blocks hide the scattered-load latency.)
__global__ __launch_bounds__(256) void k_off_a(
    const int* __restrict__ cnt, int* __restrict__ off,
    int* __restrict__ tot, int NCH)
{
    __shared__ int sm[256];
    int b = blockIdx.x;
    int t = threadIdx.x;
    int carry = 0;
    for (int c0 = 0; c0 < NCH; c0 += 256) {
        int c = c0 + t;
        int v = (c < NCH) ? cnt[c * NBK + b] : 0;
        sm[t] = v;
        __syncthreads();
        for (int o = 1; o < 256; o <<= 1) {
            int add = (t >= o) ? sm[t - o] : 0;
            __syncthreads();
            sm[t] += add;
            __syncthreads();
        }
        if (c < NCH) off[c * NBK + b] = carry + sm[t] - v;  // exclusive
        carry += sm[255];
        __syncthreads();
    }
    if (t == 0) tot[b] = carry;
}

// Pass B2: tiny single-block exclusive scan of bucket totals -> bbase.
__global__ __launch_bounds__(256) void k_off_b(
    const int* __restrict__ tot, int* __restrict__ bbase)
{
    __shared__ int sm[NBK];
    int b = threadIdx.x;
    int v0 = tot[b];
    sm[b] = v0;
    __syncthreads();
    for (int o = 1; o < NBK; o <<= 1) {
        int v = (b >= o) ? sm[b - o] : 0;
        __syncthreads();
        sm[b] += v;
        __syncthreads();
    }
    bbase[b] = sm[b] - v0;
    if (b == NBK - 1) bbase[NBK] = sm[b];
}

// Pass C: re-read chunk edges, rank via LDS cursors (init from bbase+off),
// write packed (s | (d&mask)<<17) into the chunk's exclusive slab ranges.
__global__ __launch_bounds__(256) void k_place(
    const int* __restrict__ ei, int E, int N, int shift,
    const int* __restrict__ off, const int* __restrict__ bbase,
    unsigned* __restrict__ bslab)
{
    __shared__ int cur[NBK];
    int c = blockIdx.x;
    cur[threadIdx.x] = bbase[threadIdx.x] + off[c * NBK + threadIdx.x];
    __syncthreads();
    int Etot = E + N;
    int base = c * CH;
    int lim = min(base + CH, Etot);
    int mask = (1 << shift) - 1;
    for (int e = base + threadIdx.x; e < lim; e += 256) {
        int s, d;
        if (e < E) { s = ei[e]; d = ei[E + e]; }
        else       { s = e - E; d = s; }
        int b = d >> shift;
        int pos = atomicAdd(&cur[b], 1);  // LDS atomic
        bslab[pos] = (unsigned)s | ((unsigned)(d & mask) << 17);
    }
}

// Pass D: block per bucket: LDS fine histogram + scan -> row_ptr, then place
// srcs into the bucket's csr_src window (L2-local). LDS atomics only.
__global__ __launch_bounds__(256) void k_csr2(
    const int* __restrict__ bbase, const unsigned* __restrict__ bslab,
    int shift, int* __restrict__ row_ptr, int* __restrict__ csr_src,
    int N, int Etot)
{
    __shared__ int sdeg[1024];
    __shared__ int scur[1024];
    __shared__ int ps[256];
    int b = blockIdx.x;
    int tid = threadIdx.x;
    int beg = bbase[b], end = bbase[b + 1];
    int nodes = 1 << shift;            // 512 (shift=9); LDS sized for <=1024
    int node0 = b << shift;
    for (int i = tid; i < nodes; i += 256) sdeg[i] = 0;
    __syncthreads();
    for (int i = beg + tid; i < end; i += 256)
        atomicAdd(&sdeg[bslab[i] >> 17], 1);
    __syncthreads();
    // exclusive scan over 'nodes' bins: per-thread chunk + 256-wide scan
    int per = (nodes + 255) / 256;
    int mybase = tid * per;
    int sum = 0;
    for (int j = 0; j < per; j++) sum += sdeg[mybase + j];
    ps[tid] = sum;
    __syncthreads();
    int v0 = ps[tid];
    for (int o = 1; o < 256; o <<= 1) {
        int v = (tid >= o) ? ps[tid - o] : 0;
        __syncthreads();
        ps[tid] += v;
        __syncthreads();
    }
    int run = ps[tid] - v0;
    for (int j = 0; j < per; j++) {
        int i = mybase + j;
        int dgi = sdeg[i];
        scur[i] = beg + run;
        int node = node0 + i;
        if (node < N) row_ptr[node] = beg + run;
        run += dgi;
    }
    if (b == 0 && tid == 0) row_ptr[N] = Etot;
    __syncthreads();
    for (int i = beg + tid; i < end; i += 256) {
        unsigned w = bslab[i];
        int pos = atomicAdd(&scur[w >> 17], 1);  // LDS atomic
        csr_src[pos] = (int)(w & 0x1FFFFu);
    }
}

// ===========================================================================
// xl1 = x @ W1 [N,64] -> packed bf16 pairs; as1/ad1 logits (f32).
// Thread per node; W1 (32 KB) in LDS; x read as float4.
// ===========================================================================
__global__ __launch_bounds__(256) void k_gemm1(
    const float* __restrict__ x, const float* __restrict__ W1,
    const float* __restrict__ a_src1, const float* __restrict__ a_dst1,
    unsigned* __restrict__ xl1b, float* __restrict__ as1,
    float* __restrict__ ad1, int N, int F)
{
    __shared__ float Ws[128 * 64];
    __shared__ float asrc[64];
    __shared__ float adst[64];
    for (int i = threadIdx.x; i < F * 64; i += 256) Ws[i] = W1[i];
    if (threadIdx.x < 64) {
        asrc[threadIdx.x] = a_src1[threadIdx.x];
        adst[threadIdx.x] = a_dst1[threadIdx.x];
    }
    __syncthreads();

    int n = blockIdx.x * 256 + threadIdx.x;
    if (n >= N) return;

    float acc[64];
#pragma unroll
    for (int c = 0; c < 64; c++) acc[c] = 0.0f;

    const float4* xr4 = (const float4*)(x + (size_t)n * F);
    for (int k4 = 0; k4 < F / 4; k4++) {
        float4 xv = xr4[k4];
        const float* w0 = &Ws[(k4 * 4 + 0) * 64];
        const float* w1 = &Ws[(k4 * 4 + 1) * 64];
        const float* w2 = &Ws[(k4 * 4 + 2) * 64];
        const float* w3 = &Ws[(k4 * 4 + 3) * 64];
#pragma unroll
        for (int c = 0; c < 64; c++) {
            float a = acc[c];
            a = fmaf(xv.x, w0[c], a);
            a = fmaf(xv.y, w1[c], a);
            a = fmaf(xv.z, w2[c], a);
            a = fmaf(xv.w, w3[c], a);
            acc[c] = a;
        }
    }

    unsigned* xo = xl1b + (size_t)n * 32;
#pragma unroll
    for (int p = 0; p < 32; p++) xo[p] = pack_bf16(acc[2 * p], acc[2 * p + 1]);

#pragma unroll
    for (int h = 0; h < 8; h++) {
        float s = 0.0f, t = 0.0f;
#pragma unroll
        for (int c = 0; c < 8; c++) {
            s = fmaf(acc[h * 8 + c], asrc[h * 8 + c], s);
            t = fmaf(acc[h * 8 + c], adst[h * 8 + c], t);
        }
        as1[(size_t)n * 8 + h] = s;
        ad1[(size_t)n * 8 + h] = t;
    }
}

// ===========================================================================
// Layer-1 aggregation (pull). Wave per dst. lane = 32*half + p;
// half-waves take even/odd edges, unroll x2 -> 4 gathers in flight.
// Fused: normalize + b1 + ELU -> h1[d,64] f32.
// ===========================================================================
__global__ __launch_bounds__(256) void k_agg1(
    const int* __restrict__ row_ptr, const int* __restrict__ csr_src,
    const float* __restrict__ as1, const float* __restrict__ ad1,
    const unsigned* __restrict__ xl1b, const float* __restrict__ b1,
    float* __restrict__ h1, int N)
{
    int d = blockIdx.x * 4 + (threadIdx.x >> 6);
    int lane = threadIdx.x & 63;
    if (d >= N) return;
    int half = lane >> 5;
    int p = lane & 31;          // channel pair
    int h = p >> 2;             // head of channels 2p,2p+1

    int beg = row_ptr[d];
    int end = row_ptr[d + 1];
    float adh = ad1[(size_t)d * 8 + h];

    float ax0 = 0.f, ay0 = 0.f, dn0 = 0.f;
    float ax1 = 0.f, ay1 = 0.f, dn1 = 0.f;
    int i = beg + half;
    for (; i + 2 < end; i += 4) {
        int s0 = csr_src[i];
        int s1 = csr_src[i + 2];
        float al0 = as1[(size_t)s0 * 8 + h] + adh;
        float al1 = as1[(size_t)s1 * 8 + h] + adh;
        unsigned k0 = xl1b[(size_t)s0 * 32 + p];
        unsigned k1 = xl1b[(size_t)s1 * 32 + p];
        al0 = al0 > 0.f ? al0 : NEG_SLOPE * al0;
        al1 = al1 > 0.f ? al1 : NEG_SLOPE * al1;
        float e0 = __expf(al0);
        float e1 = __expf(al1);
        ax0 = fmaf(e0, bf_lo(k0), ax0); ay0 = fmaf(e0, bf_hi(k0), ay0); dn0 += e0;
        ax1 = fmaf(e1, bf_lo(k1), ax1); ay1 = fmaf(e1, bf_hi(k1), ay1); dn1 += e1;
    }
    if (i < end) {
        int s0 = csr_src[i];
        float al0 = as1[(size_t)s0 * 8 + h] + adh;
        unsigned k0 = xl1b[(size_t)s0 * 32 + p];
        al0 = al0 > 0.f ? al0 : NEG_SLOPE * al0;
        float e0 = __expf(al0);
        ax0 = fmaf(e0, bf_lo(k0), ax0); ay0 = fmaf(e0, bf_hi(k0), ay0); dn0 += e0;
    }

    float ax = ax0 + ax1, ay = ay0 + ay1, den = dn0 + dn1;
    ax += __shfl_xor(ax, 32);
    ay += __shfl_xor(ay, 32);
    den += __shfl_xor(den, 32);

    if (half == 0) {
        float inv = 1.0f / (den + GAT_EPS);
        float2 bv = ((const float2*)b1)[p];
        float hx = ax * inv + bv.x;
        float hy = ay * inv + bv.y;
        hx = hx > 0.f ? hx : expm1f(hx);
        hy = hy > 0.f ? hy : expm1f(hy);
        ((float2*)(h1 + (size_t)d * 64))[p] = make_float2(hx, hy);
    }
}

// ===========================================================================
// Layer-2 node transform: xl2 = h1 @ W2 [N,40] -> packed bf16; as2/ad2.
// ===========================================================================
__global__ __launch_bounds__(256) void k_node2(
    const float* __restrict__ h1, const float* __restrict__ W2,
    const float* __restrict__ a_src2, const float* __restrict__ a_dst2,
    unsigned* __restrict__ xl2b, float* __restrict__ as2,
    float* __restrict__ ad2, int N)
{
    __shared__ float Ws[64 * 40];
    __shared__ float a2s[40];
    __shared__ float a2d[40];
    for (int i = threadIdx.x; i < 64 * 40; i += 256) Ws[i] = W2[i];
    if (threadIdx.x < 40) {
        a2s[threadIdx.x] = a_src2[threadIdx.x];
        a2d[threadIdx.x] = a_dst2[threadIdx.x];
    }
    __syncthreads();

    int n = blockIdx.x * 256 + threadIdx.x;
    if (n >= N) return;

    float o[40];
#pragma unroll
    for (int j = 0; j < 40; j++) o[j] = 0.0f;

    const float* hr = h1 + (size_t)n * 64;
    for (int k = 0; k < 64; k++) {
        float hk = hr[k];
#pragma unroll
        for (int j = 0; j < 40; j++) o[j] = fmaf(hk, Ws[k * 40 + j], o[j]);
    }

    float s = 0.0f, t = 0.0f;
    unsigned* xo = xl2b + (size_t)n * 20;
#pragma unroll
    for (int j = 0; j < 40; j++) {
        s = fmaf(o[j], a2s[j], s);
        t = fmaf(o[j], a2d[j], t);
    }
#pragma unroll
    for (int p = 0; p < 20; p++) xo[p] = pack_bf16(o[2 * p], o[2 * p + 1]);
    as2[n] = s;
    ad2[n] = t;
}

// ===========================================================================
// Layer-2 aggregation (pull). Wave per dst; pairs p=0..19 active for data.
// Writes d_out directly.
// ===========================================================================
__global__ __launch_bounds__(256) void k_agg2(
    const int* __restrict__ row_ptr, const int* __restrict__ csr_src,
    const float* __restrict__ as2, const float* __restrict__ ad2,
    const unsigned* __restrict__ xl2b, const float* __restrict__ b2,
    float* __restrict__ out, int N)
{
    int d = blockIdx.x * 4 + (threadIdx.x >> 6);
    int lane = threadIdx.x & 63;
    if (d >= N) return;
    int half = lane >> 5;
    int p = lane & 31;          // channel pair, active if p<20

    int beg = row_ptr[d];
    int end = row_ptr[d + 1];
    float add = ad2[d];
    bool act = (p < 20);
    int pc = act ? p : 0;

    float ax0 = 0.f, ay0 = 0.f, dn0 = 0.f;
    float ax1 = 0.f, ay1 = 0.f, dn1 = 0.f;
    int i = beg + half;
    for (; i + 2 < end; i += 4) {
        int s0 = csr_src[i];
        int s1 = csr_src[i + 2];
        float al0 = as2[s0] + add;
        float al1 = as2[s1] + add;
        unsigned k0 = xl2b[(size_t)s0 * 20 + pc];
        unsigned k1 = xl2b[(size_t)s1 * 20 + pc];
        al0 = al0 > 0.f ? al0 : NEG_SLOPE * al0;
        al1 = al1 > 0.f ? al1 : NEG_SLOPE * al1;
        float e0 = __expf(al0);
        float e1 = __expf(al1);
        ax0 = fmaf(e0, bf_lo(k0), ax0); ay0 = fmaf(e0, bf_hi(k0), ay0); dn0 += e0;
        ax1 = fmaf(e1, bf_lo(k1), ax1); ay1 = fmaf(e1, bf_hi(k1), ay1); dn1 += e1;
    }
    if (i < end) {
        int s0 = csr_src[i];
        float al0 = as2[s0] + add;
        unsigned k0 = xl2b[(size_t)s0 * 20 + pc];
        al0 = al0 > 0.f ? al0 : NEG_SLOPE * al0;
        float e0 = __expf(al0);
        ax0 = fmaf(e0, bf_lo(k0), ax0); ay0 = fmaf(e0, bf_hi(k0), ay0); dn0 += e0;
    }

    float ax = ax0 + ax1, ay = ay0 + ay1, den = dn0 + dn1;
    ax += __shfl_xor(ax, 32);
    ay += __shfl_xor(ay, 32);
    den += __shfl_xor(den, 32);

    if (half == 0 && act) {
        float inv = 1.0f / (den + GAT_EPS);
        float2 bv = ((const float2*)b2)[p];
        ((float2*)(out + (size_t)d * 40))[p] =
            make_float2(ax * inv + bv.x, ay * inv + bv.y);
    }
}

extern "C" void kernel_launch(void* const* d_in, const int* in_sizes, int n_in,
                              void* d_out, int out_size, void* d_ws, size_t ws_size,
                              hipStream_t stream) {
    const float* x      = (const float*)d_in[0];
    const int*   ei     = (const int*)d_in[1];     // int32 on device
    const float* W1     = (const float*)d_in[2];
    const float* a_src1 = (const float*)d_in[3];
    const float* a_dst1 = (const float*)d_in[4];
    const float* b1     = (const float*)d_in[5];
    const float* W2     = (const float*)d_in[6];
    const float* a_src2 = (const float*)d_in[7];
    const float* a_dst2 = (const float*)d_in[8];
    const float* b2     = (const float*)d_in[9];

    int F = in_sizes[2] / 64;      // 128
    int N = in_sizes[0] / F;       // 100000
    int E = in_sizes[1] / 2;       // 1600000
    int Etot = E + N;
    int NCH = (Etot + CH - 1) / CH;  // 208 chunks
    int shift = 9;                   // 512 nodes/bucket; N<131072 -> <=196 buckets
    while (((N - 1) >> shift) >= NBK) shift++;  // safety (LDS supports shift<=10)

    // Workspace (4-byte words). Peak ~59 MB.
    unsigned* xl1b    = (unsigned*)d_ws;                   // N*32
    float*    h1      = (float*)(xl1b + (size_t)N * 32);   // N*64
    float*    as1     = h1 + (size_t)N * 64;               // N*8
    float*    ad1     = as1 + (size_t)N * 8;               // N*8
    int*      row_ptr = (int*)(ad1 + (size_t)N * 8);       // N+1
    int*      csr_src = row_ptr + (N + 1);                 // Etot
    int*      cnt     = csr_src + Etot;                    // NCH*NBK
    int*      off     = cnt + (size_t)NCH * NBK;           // NCH*NBK
    int*      tot     = off + (size_t)NCH * NBK;           // NBK
    int*      bbase   = tot + NBK;                         // NBK+1
    unsigned* bslab   = (unsigned*)(bbase + NBK + 1);      // Etot
    // Aliases (live only after k_agg1; originals dead by then):
    unsigned* xl2b    = xl1b;                              // N*20 <= N*32
    float*    as2     = as1;                               // N
    float*    ad2     = ad1;                               // N

    // ---- CSR build: deterministic counting sort, zero global atomics ----
    k_cnt  <<<NCH, 256, 0, stream>>>(ei, E, N, shift, cnt);
    k_off_a<<<NBK, 256, 0, stream>>>(cnt, off, tot, NCH);
    k_off_b<<<1, 256, 0, stream>>>(tot, bbase);
    k_place<<<NCH, 256, 0, stream>>>(ei, E, N, shift, off, bbase, bslab);
    k_csr2 <<<NBK, 256, 0, stream>>>(bbase, bslab, shift,
                                     row_ptr, csr_src, N, Etot);

    // ---- Layer 1 ----
    k_gemm1<<<(N + 255) / 256, 256, 0, stream>>>(x, W1, a_src1, a_dst1,
                                                 xl1b, as1, ad1, N, F);
    k_agg1 <<<(N + 3) / 4, 256, 0, stream>>>(row_ptr, csr_src, as1, ad1,
                                             xl1b, b1, h1, N);

    // ---- Layer 2 ----
    k_node2<<<(N + 255) / 256, 256, 0, stream>>>(h1, W2, a_src2, a_dst2,
                                                 xl2b, as2, ad2, N);
    k_agg2 <<<(N + 3) / 4, 256, 0, stream>>>(row_ptr, csr_src, as2, ad2,
                                             xl2b, b2, (float*)d_out, N);
}

// Round 8
// 345.705 us; speedup vs baseline: 1.7764x; 1.0799x over previous
//
#include <hip/hip_runtime.h>
#include <math.h>

#define NEG_SLOPE 0.2f
#define GAT_EPS 1e-16f

#define CH   8192   // edges per chunk (k_cnt / k_place)
#define NBK  256    // coarse buckets; bucket = d >> SHIFT (512 nodes/bucket)
// Pack constraint: s < 2^17 (N <= 131072) and (d & 511) in bits 17..25.

// ---- bf16 pair packing helpers (channel 2p in low half, 2p+1 in high) ----
__device__ __forceinline__ unsigned pack_bf16(float a, float b) {
    unsigned ua = __float_as_uint(a);
    unsigned ub = __float_as_uint(b);
    ua = (ua + 0x8000u) >> 16;
    ub = (ub + 0x8000u) & 0xffff0000u;
    return ua | ub;
}
__device__ __forceinline__ float bf_lo(unsigned pk) {
    return __uint_as_float(pk << 16);
}
__device__ __forceinline__ float bf_hi(unsigned pk) {
    return __uint_as_float(pk & 0xffff0000u);
}

// ===========================================================================
// CSR build via deterministic two-level counting sort — ZERO global atomics.
// Edge ids e >= E are self-loops (s = d = e - E). ei[0..E)=src, ei[E..2E)=dst.
// ===========================================================================

// Pass A: per-chunk LDS histogram over coarse buckets -> cnt[chunk][NBK].
__global__ __launch_bounds__(256) void k_cnt(
    const int* __restrict__ ei, int E, int N, int shift,
    int* __restrict__ cnt)
{
    __shared__ int h[NBK];
    int c = blockIdx.x;
    h[threadIdx.x] = 0;
    __syncthreads();
    int Etot = E + N;
    int base = c * CH;
    int lim = min(base + CH, Etot);
    for (int e = base + threadIdx.x; e < lim; e += 256) {
        int d = (e < E) ? ei[E + e] : (e - E);
        atomicAdd(&h[d >> shift], 1);
    }
    __syncthreads();
    cnt[c * NBK + threadIdx.x] = h[threadIdx.x];
}

// Pass B1: PARALLEL per-bucket scan over chunks (block = bucket).
__global__ __launch_bounds__(256) void k_off_a(
    const int* __restrict__ cnt, int* __restrict__ off,
    int* __restrict__ tot, int NCH)
{
    __shared__ int sm[256];
    int b = blockIdx.x;
    int t = threadIdx.x;
    int carry = 0;
    for (int c0 = 0; c0 < NCH; c0 += 256) {
        int c = c0 + t;
        int v = (c < NCH) ? cnt[c * NBK + b] : 0;
        sm[t] = v;
        __syncthreads();
        for (int o = 1; o < 256; o <<= 1) {
            int add = (t >= o) ? sm[t - o] : 0;
            __syncthreads();
            sm[t] += add;
            __syncthreads();
        }
        if (c < NCH) off[c * NBK + b] = carry + sm[t] - v;  // exclusive
        carry += sm[255];
        __syncthreads();
    }
    if (t == 0) tot[b] = carry;
}

// Pass B2: tiny single-block exclusive scan of bucket totals -> bbase.
__global__ __launch_bounds__(256) void k_off_b(
    const int* __restrict__ tot, int* __restrict__ bbase)
{
    __shared__ int sm[NBK];
    int b = threadIdx.x;
    int v0 = tot[b];
    sm[b] = v0;
    __syncthreads();
    for (int o = 1; o < NBK; o <<= 1) {
        int v = (b >= o) ? sm[b - o] : 0;
        __syncthreads();
        sm[b] += v;
        __syncthreads();
    }
    bbase[b] = sm[b] - v0;
    if (b == NBK - 1) bbase[NBK] = sm[b];
}

// Pass C: re-read chunk edges, rank via LDS cursors (init from bbase+off),
// write packed (s | (d&mask)<<17) into the chunk's exclusive slab ranges.
__global__ __launch_bounds__(256) void k_place(
    const int* __restrict__ ei, int E, int N, int shift,
    const int* __restrict__ off, const int* __restrict__ bbase,
    unsigned* __restrict__ bslab)
{
    __shared__ int cur[NBK];
    int c = blockIdx.x;
    cur[threadIdx.x] = bbase[threadIdx.x] + off[c * NBK + threadIdx.x];
    __syncthreads();
    int Etot = E + N;
    int base = c * CH;
    int lim = min(base + CH, Etot);
    int mask = (1 << shift) - 1;
    for (int e = base + threadIdx.x; e < lim; e += 256) {
        int s, d;
        if (e < E) { s = ei[e]; d = ei[E + e]; }
        else       { s = e - E; d = s; }
        int b = d >> shift;
        int pos = atomicAdd(&cur[b], 1);  // LDS atomic
        bslab[pos] = (unsigned)s | ((unsigned)(d & mask) << 17);
    }
}

// Pass D: block per bucket: LDS fine histogram + scan -> row_ptr, then place
// srcs into the bucket's csr_src window (L2-local). LDS atomics only.
__global__ __launch_bounds__(256) void k_csr2(
    const int* __restrict__ bbase, const unsigned* __restrict__ bslab,
    int shift, int* __restrict__ row_ptr, int* __restrict__ csr_src,
    int N, int Etot)
{
    __shared__ int sdeg[1024];
    __shared__ int scur[1024];
    __shared__ int ps[256];
    int b = blockIdx.x;
    int tid = threadIdx.x;
    int beg = bbase[b], end = bbase[b + 1];
    int nodes = 1 << shift;            // 512 (shift=9); LDS sized for <=1024
    int node0 = b << shift;
    for (int i = tid; i < nodes; i += 256) sdeg[i] = 0;
    __syncthreads();
    for (int i = beg + tid; i < end; i += 256)
        atomicAdd(&sdeg[bslab[i] >> 17], 1);
    __syncthreads();
    int per = (nodes + 255) / 256;
    int mybase = tid * per;
    int sum = 0;
    for (int j = 0; j < per; j++) sum += sdeg[mybase + j];
    ps[tid] = sum;
    __syncthreads();
    int v0 = ps[tid];
    for (int o = 1; o < 256; o <<= 1) {
        int v = (tid >= o) ? ps[tid - o] : 0;
        __syncthreads();
        ps[tid] += v;
        __syncthreads();
    }
    int run = ps[tid] - v0;
    for (int j = 0; j < per; j++) {
        int i = mybase + j;
        int dgi = sdeg[i];
        scur[i] = beg + run;
        int node = node0 + i;
        if (node < N) row_ptr[node] = beg + run;
        run += dgi;
    }
    if (b == 0 && tid == 0) row_ptr[N] = Etot;
    __syncthreads();
    for (int i = beg + tid; i < end; i += 256) {
        unsigned w = bslab[i];
        int pos = atomicAdd(&scur[w >> 17], 1);  // LDS atomic
        csr_src[pos] = (int)(w & 0x1FFFFu);
    }
}

// ===========================================================================
// xl1 = x @ W1 [N,64] -> packed bf16 pairs; as1/ad1 logits (f32).
// Thread per node; W1 (32 KB) in LDS; x read as float4.
// ===========================================================================
__global__ __launch_bounds__(256) void k_gemm1(
    const float* __restrict__ x, const float* __restrict__ W1,
    const float* __restrict__ a_src1, const float* __restrict__ a_dst1,
    unsigned* __restrict__ xl1b, float* __restrict__ as1,
    float* __restrict__ ad1, int N, int F)
{
    __shared__ float Ws[128 * 64];
    __shared__ float asrc[64];
    __shared__ float adst[64];
    for (int i = threadIdx.x; i < F * 64; i += 256) Ws[i] = W1[i];
    if (threadIdx.x < 64) {
        asrc[threadIdx.x] = a_src1[threadIdx.x];
        adst[threadIdx.x] = a_dst1[threadIdx.x];
    }
    __syncthreads();

    int n = blockIdx.x * 256 + threadIdx.x;
    if (n >= N) return;

    float acc[64];
#pragma unroll
    for (int c = 0; c < 64; c++) acc[c] = 0.0f;

    const float4* xr4 = (const float4*)(x + (size_t)n * F);
    for (int k4 = 0; k4 < F / 4; k4++) {
        float4 xv = xr4[k4];
        const float* w0 = &Ws[(k4 * 4 + 0) * 64];
        const float* w1 = &Ws[(k4 * 4 + 1) * 64];
        const float* w2 = &Ws[(k4 * 4 + 2) * 64];
        const float* w3 = &Ws[(k4 * 4 + 3) * 64];
#pragma unroll
        for (int c = 0; c < 64; c++) {
            float a = acc[c];
            a = fmaf(xv.x, w0[c], a);
            a = fmaf(xv.y, w1[c], a);
            a = fmaf(xv.z, w2[c], a);
            a = fmaf(xv.w, w3[c], a);
            acc[c] = a;
        }
    }

    unsigned* xo = xl1b + (size_t)n * 32;
#pragma unroll
    for (int p = 0; p < 32; p++) xo[p] = pack_bf16(acc[2 * p], acc[2 * p + 1]);

#pragma unroll
    for (int h = 0; h < 8; h++) {
        float s = 0.0f, t = 0.0f;
#pragma unroll
        for (int c = 0; c < 8; c++) {
            s = fmaf(acc[h * 8 + c], asrc[h * 8 + c], s);
            t = fmaf(acc[h * 8 + c], adst[h * 8 + c], t);
        }
        as1[(size_t)n * 8 + h] = s;
        ad1[(size_t)n * 8 + h] = t;
    }
}

// ===========================================================================
// Layer-1 aggregation (pull), 8-lanes-per-edge layout.
// Wave per dst. lane = 8*g + l: g = edge group (8 edges in flight),
// l = head AND channel-octet (channels 8l..8l+7 via one uint4 = 8 bf16).
// Head-aligned: exp computed once per head, zero redundancy. Cross-group
// combine via shfl_xor strides 8/16/32. Fused normalize + b1 + ELU.
// (Replaces 32-lane/edge version: VALUBusy was 63% with ~75% of lane-ops
// being per-edge overhead replicated 32x; this cuts it ~2.3x and doubles
// the number of independent gathers in flight.)
// ===========================================================================
__global__ __launch_bounds__(256) void k_agg1(
    const int* __restrict__ row_ptr, const int* __restrict__ csr_src,
    const float* __restrict__ as1, const float* __restrict__ ad1,
    const unsigned* __restrict__ xl1b, const float* __restrict__ b1,
    float* __restrict__ h1, int N)
{
    int d = blockIdx.x * 4 + (threadIdx.x >> 6);
    int lane = threadIdx.x & 63;
    if (d >= N) return;
    int g = lane >> 3;   // edge group
    int l = lane & 7;    // head / channel octet

    int beg = row_ptr[d], end = row_ptr[d + 1];
    float adh = ad1[(size_t)d * 8 + l];

    float ax[8];
#pragma unroll
    for (int j = 0; j < 8; j++) ax[j] = 0.f;
    float den = 0.f;

    for (int i = beg + g; i < end; i += 8) {
        int s = csr_src[i];
        float al = as1[(size_t)s * 8 + l] + adh;
        al = al > 0.f ? al : NEG_SLOPE * al;
        float e = __expf(al);
        uint4 k = *(const uint4*)(xl1b + (size_t)s * 32 + l * 4);
        ax[0] = fmaf(e, bf_lo(k.x), ax[0]);
        ax[1] = fmaf(e, bf_hi(k.x), ax[1]);
        ax[2] = fmaf(e, bf_lo(k.y), ax[2]);
        ax[3] = fmaf(e, bf_hi(k.y), ax[3]);
        ax[4] = fmaf(e, bf_lo(k.z), ax[4]);
        ax[5] = fmaf(e, bf_hi(k.z), ax[5]);
        ax[6] = fmaf(e, bf_lo(k.w), ax[6]);
        ax[7] = fmaf(e, bf_hi(k.w), ax[7]);
        den += e;
    }

#pragma unroll
    for (int m = 8; m < 64; m <<= 1) {
#pragma unroll
        for (int j = 0; j < 8; j++) ax[j] += __shfl_xor(ax[j], m);
        den += __shfl_xor(den, m);
    }

    if (g == 0) {
        float inv = 1.f / (den + GAT_EPS);
        const float4* bb = (const float4*)(b1 + l * 8);
        float4 b0 = bb[0], b1v = bb[1];
        float4 o0, o1;
        float v;
        v = ax[0] * inv + b0.x; o0.x = v > 0.f ? v : expm1f(v);
        v = ax[1] * inv + b0.y; o0.y = v > 0.f ? v : expm1f(v);
        v = ax[2] * inv + b0.z; o0.z = v > 0.f ? v : expm1f(v);
        v = ax[3] * inv + b0.w; o0.w = v > 0.f ? v : expm1f(v);
        v = ax[4] * inv + b1v.x; o1.x = v > 0.f ? v : expm1f(v);
        v = ax[5] * inv + b1v.y; o1.y = v > 0.f ? v : expm1f(v);
        v = ax[6] * inv + b1v.z; o1.z = v > 0.f ? v : expm1f(v);
        v = ax[7] * inv + b1v.w; o1.w = v > 0.f ? v : expm1f(v);
        float4* op = (float4*)(h1 + (size_t)d * 64 + l * 8);
        op[0] = o0;
        op[1] = o1;
    }
}

// ===========================================================================
// Layer-2 node transform: xl2 = h1 @ W2 [N,40] -> packed bf16 in rows of
// stride 32 uints (channels 20..31 are don't-care pad; agg2 ignores them).
// ===========================================================================
__global__ __launch_bounds__(256) void k_node2(
    const float* __restrict__ h1, const float* __restrict__ W2,
    const float* __restrict__ a_src2, const float* __restrict__ a_dst2,
    unsigned* __restrict__ xl2b, float* __restrict__ as2,
    float* __restrict__ ad2, int N)
{
    __shared__ float Ws[64 * 40];
    __shared__ float a2s[40];
    __shared__ float a2d[40];
    for (int i = threadIdx.x; i < 64 * 40; i += 256) Ws[i] = W2[i];
    if (threadIdx.x < 40) {
        a2s[threadIdx.x] = a_src2[threadIdx.x];
        a2d[threadIdx.x] = a_dst2[threadIdx.x];
    }
    __syncthreads();

    int n = blockIdx.x * 256 + threadIdx.x;
    if (n >= N) return;

    float o[40];
#pragma unroll
    for (int j = 0; j < 40; j++) o[j] = 0.0f;

    const float* hr = h1 + (size_t)n * 64;
    for (int k = 0; k < 64; k++) {
        float hk = hr[k];
#pragma unroll
        for (int j = 0; j < 40; j++) o[j] = fmaf(hk, Ws[k * 40 + j], o[j]);
    }

    float s = 0.0f, t = 0.0f;
    unsigned* xo = xl2b + (size_t)n * 32;
#pragma unroll
    for (int j = 0; j < 40; j++) {
        s = fmaf(o[j], a2s[j], s);
        t = fmaf(o[j], a2d[j], t);
    }
#pragma unroll
    for (int p = 0; p < 20; p++) xo[p] = pack_bf16(o[2 * p], o[2 * p + 1]);
    as2[n] = s;
    ad2[n] = t;
}

// ===========================================================================
// Layer-2 aggregation (pull), 8-lanes-per-edge. Same layout as k_agg1;
// H=1 so every lane's exp is its own copy (den converges after the
// g-reduction). Only l<5 octets hold real channels (40 = 5*8); l>=5 read
// pad (finite garbage) and never store. Writes d_out directly.
// ===========================================================================
__global__ __launch_bounds__(256) void k_agg2(
    const int* __restrict__ row_ptr, const int* __restrict__ csr_src,
    const float* __restrict__ as2, const float* __restrict__ ad2,
    const unsigned* __restrict__ xl2b, const float* __restrict__ b2,
    float* __restrict__ out, int N)
{
    int d = blockIdx.x * 4 + (threadIdx.x >> 6);
    int lane = threadIdx.x & 63;
    if (d >= N) return;
    int g = lane >> 3;
    int l = lane & 7;

    int beg = row_ptr[d], end = row_ptr[d + 1];
    float add = ad2[d];

    float ax[8];
#pragma unroll
    for (int j = 0; j < 8; j++) ax[j] = 0.f;
    float den = 0.f;

    for (int i = beg + g; i < end; i += 8) {
        int s = csr_src[i];
        float al = as2[s] + add;
        al = al > 0.f ? al : NEG_SLOPE * al;
        float e = __expf(al);
        uint4 k = *(const uint4*)(xl2b + (size_t)s * 32 + l * 4);
        ax[0] = fmaf(e, bf_lo(k.x), ax[0]);
        ax[1] = fmaf(e, bf_hi(k.x), ax[1]);
        ax[2] = fmaf(e, bf_lo(k.y), ax[2]);
        ax[3] = fmaf(e, bf_hi(k.y), ax[3]);
        ax[4] = fmaf(e, bf_lo(k.z), ax[4]);
        ax[5] = fmaf(e, bf_hi(k.z), ax[5]);
        ax[6] = fmaf(e, bf_lo(k.w), ax[6]);
        ax[7] = fmaf(e, bf_hi(k.w), ax[7]);
        den += e;
    }

#pragma unroll
    for (int m = 8; m < 64; m <<= 1) {
#pragma unroll
        for (int j = 0; j < 8; j++) ax[j] += __shfl_xor(ax[j], m);
        den += __shfl_xor(den, m);
    }

    if (g == 0 && l < 5) {
        float inv = 1.f / (den + GAT_EPS);
        float* op = out + (size_t)d * 40 + l * 8;
        const float* bb = b2 + l * 8;
#pragma unroll
        for (int j = 0; j < 8; j++) op[j] = ax[j] * inv + bb[j];
    }
}

extern "C" void kernel_launch(void* const* d_in, const int* in_sizes, int n_in,
                              void* d_out, int out_size, void* d_ws, size_t ws_size,
                              hipStream_t stream) {
    const float* x      = (const float*)d_in[0];
    const int*   ei     = (const int*)d_in[1];     // int32 on device
    const float* W1     = (const float*)d_in[2];
    const float* a_src1 = (const float*)d_in[3];
    const float* a_dst1 = (const float*)d_in[4];
    const float* b1     = (const float*)d_in[5];
    const float* W2     = (const float*)d_in[6];
    const float* a_src2 = (const float*)d_in[7];
    const float* a_dst2 = (const float*)d_in[8];
    const float* b2     = (const float*)d_in[9];

    int F = in_sizes[2] / 64;      // 128
    int N = in_sizes[0] / F;       // 100000
    int E = in_sizes[1] / 2;       // 1600000
    int Etot = E + N;
    int NCH = (Etot + CH - 1) / CH;  // 208 chunks
    int shift = 9;                   // 512 nodes/bucket; N<131072 -> <=196 buckets
    while (((N - 1) >> shift) >= NBK) shift++;  // safety (LDS supports shift<=10)

    // Workspace (4-byte words). Peak ~59 MB.
    unsigned* xl1b    = (unsigned*)d_ws;                   // N*32
    float*    h1      = (float*)(xl1b + (size_t)N * 32);   // N*64
    float*    as1     = h1 + (size_t)N * 64;               // N*8
    float*    ad1     = as1 + (size_t)N * 8;               // N*8
    int*      row_ptr = (int*)(ad1 + (size_t)N * 8);       // N+1
    int*      csr_src = row_ptr + (N + 1);                 // Etot
    int*      cnt     = csr_src + Etot;                    // NCH*NBK
    int*      off     = cnt + (size_t)NCH * NBK;           // NCH*NBK
    int*      tot     = off + (size_t)NCH * NBK;           // NBK
    int*      bbase   = tot + NBK;                         // NBK+1
    unsigned* bslab   = (unsigned*)(bbase + NBK + 1);      // Etot
    // Aliases (live only after k_agg1; originals dead by then):
    unsigned* xl2b    = xl1b;                              // N*32 (padded rows)
    float*    as2     = as1;                               // N
    float*    ad2     = ad1;                               // N

    // ---- CSR build: deterministic counting sort, zero global atomics ----
    k_cnt  <<<NCH, 256, 0, stream>>>(ei, E, N, shift, cnt);
    k_off_a<<<NBK, 256, 0, stream>>>(cnt, off, tot, NCH);
    k_off_b<<<1, 256, 0, stream>>>(tot, bbase);
    k_place<<<NCH, 256, 0, stream>>>(ei, E, N, shift, off, bbase, bslab);
    k_csr2 <<<NBK, 256, 0, stream>>>(bbase, bslab, shift,
                                     row_ptr, csr_src, N, Etot);

    // ---- Layer 1 ----
    k_gemm1<<<(N + 255) / 256, 256, 0, stream>>>(x, W1, a_src1, a_dst1,
                                                 xl1b, as1, ad1, N, F);
    k_agg1 <<<(N + 3) / 4, 256, 0, stream>>>(row_ptr, csr_src, as1, ad1,
                                             xl1b, b1, h1, N);

    // ---- Layer 2 ----
    k_node2<<<(N + 255) / 256, 256, 0, stream>>>(h1, W2, a_src2, a_dst2,
                                                 xl2b, as2, ad2, N);
    k_agg2 <<<(N + 3) / 4, 256, 0, stream>>>(row_ptr, csr_src, as2, ad2,
                                             xl2b, b2, (float*)d_out, N);
}

// Round 9
// 320.788 us; speedup vs baseline: 1.9144x; 1.0777x over previous
//
#include <hip/hip_runtime.h>
#include <math.h>

#define NEG_SLOPE 0.2f
#define GAT_EPS 1e-16f

#define CH   8192   // edges per chunk (k_cnt / k_place)
#define NBK  256    // coarse buckets; bucket = d >> SHIFT (512 nodes/bucket)
// Pack constraint: s < 2^17 (N <= 131072) and (d & 511) in bits 17..25.

// ---- bf16 pair packing helpers (channel 2p in low half, 2p+1 in high) ----
__device__ __forceinline__ unsigned pack_bf16(float a, float b) {
    unsigned ua = __float_as_uint(a);
    unsigned ub = __float_as_uint(b);
    ua = (ua + 0x8000u) >> 16;
    ub = (ub + 0x8000u) & 0xffff0000u;
    return ua | ub;
}
__device__ __forceinline__ float bf_lo(unsigned pk) {
    return __uint_as_float(pk << 16);
}
__device__ __forceinline__ float bf_hi(unsigned pk) {
    return __uint_as_float(pk & 0xffff0000u);
}

// ===========================================================================
// CSR build via deterministic two-level counting sort — ZERO global atomics.
// Edge ids e >= E are self-loops (s = d = e - E). ei[0..E)=src, ei[E..2E)=dst.
// ===========================================================================

// Pass A: per-chunk LDS histogram over coarse buckets -> cnt[chunk][NBK].
__global__ __launch_bounds__(256) void k_cnt(
    const int* __restrict__ ei, int E, int N, int shift,
    int* __restrict__ cnt)
{
    __shared__ int h[NBK];
    int c = blockIdx.x;
    h[threadIdx.x] = 0;
    __syncthreads();
    int Etot = E + N;
    int base = c * CH;
    int lim = min(base + CH, Etot);
    for (int e = base + threadIdx.x; e < lim; e += 256) {
        int d = (e < E) ? ei[E + e] : (e - E);
        atomicAdd(&h[d >> shift], 1);
    }
    __syncthreads();
    cnt[c * NBK + threadIdx.x] = h[threadIdx.x];
}

// Pass B1: PARALLEL per-bucket scan over chunks (block = bucket).
__global__ __launch_bounds__(256) void k_off_a(
    const int* __restrict__ cnt, int* __restrict__ off,
    int* __restrict__ tot, int NCH)
{
    __shared__ int sm[256];
    int b = blockIdx.x;
    int t = threadIdx.x;
    int carry = 0;
    for (int c0 = 0; c0 < NCH; c0 += 256) {
        int c = c0 + t;
        int v = (c < NCH) ? cnt[c * NBK + b] : 0;
        sm[t] = v;
        __syncthreads();
        for (int o = 1; o < 256; o <<= 1) {
            int add = (t >= o) ? sm[t - o] : 0;
            __syncthreads();
            sm[t] += add;
            __syncthreads();
        }
        if (c < NCH) off[c * NBK + b] = carry + sm[t] - v;  // exclusive
        carry += sm[255];
        __syncthreads();
    }
    if (t == 0) tot[b] = carry;
}

// Pass B2: tiny single-block exclusive scan of bucket totals -> bbase.
__global__ __launch_bounds__(256) void k_off_b(
    const int* __restrict__ tot, int* __restrict__ bbase)
{
    __shared__ int sm[NBK];
    int b = threadIdx.x;
    int v0 = tot[b];
    sm[b] = v0;
    __syncthreads();
    for (int o = 1; o < NBK; o <<= 1) {
        int v = (b >= o) ? sm[b - o] : 0;
        __syncthreads();
        sm[b] += v;
        __syncthreads();
    }
    bbase[b] = sm[b] - v0;
    if (b == NBK - 1) bbase[NBK] = sm[b];
}

// Pass C: re-read chunk edges, rank via LDS cursors (init from bbase+off),
// write packed (s | (d&mask)<<17) into the chunk's exclusive slab ranges.
__global__ __launch_bounds__(256) void k_place(
    const int* __restrict__ ei, int E, int N, int shift,
    const int* __restrict__ off, const int* __restrict__ bbase,
    unsigned* __restrict__ bslab)
{
    __shared__ int cur[NBK];
    int c = blockIdx.x;
    cur[threadIdx.x] = bbase[threadIdx.x] + off[c * NBK + threadIdx.x];
    __syncthreads();
    int Etot = E + N;
    int base = c * CH;
    int lim = min(base + CH, Etot);
    int mask = (1 << shift) - 1;
    for (int e = base + threadIdx.x; e < lim; e += 256) {
        int s, d;
        if (e < E) { s = ei[e]; d = ei[E + e]; }
        else       { s = e - E; d = s; }
        int b = d >> shift;
        int pos = atomicAdd(&cur[b], 1);  // LDS atomic
        bslab[pos] = (unsigned)s | ((unsigned)(d & mask) << 17);
    }
}

// Pass D: block per bucket: LDS fine histogram + scan -> row_ptr, then place
// srcs into the bucket's csr_src window (L2-local). LDS atomics only.
__global__ __launch_bounds__(256) void k_csr2(
    const int* __restrict__ bbase, const unsigned* __restrict__ bslab,
    int shift, int* __restrict__ row_ptr, int* __restrict__ csr_src,
    int N, int Etot)
{
    __shared__ int sdeg[1024];
    __shared__ int scur[1024];
    __shared__ int ps[256];
    int b = blockIdx.x;
    int tid = threadIdx.x;
    int beg = bbase[b], end = bbase[b + 1];
    int nodes = 1 << shift;            // 512 (shift=9); LDS sized for <=1024
    int node0 = b << shift;
    for (int i = tid; i < nodes; i += 256) sdeg[i] = 0;
    __syncthreads();
    for (int i = beg + tid; i < end; i += 256)
        atomicAdd(&sdeg[bslab[i] >> 17], 1);
    __syncthreads();
    int per = (nodes + 255) / 256;
    int mybase = tid * per;
    int sum = 0;
    for (int j = 0; j < per; j++) sum += sdeg[mybase + j];
    ps[tid] = sum;
    __syncthreads();
    int v0 = ps[tid];
    for (int o = 1; o < 256; o <<= 1) {
        int v = (tid >= o) ? ps[tid - o] : 0;
        __syncthreads();
        ps[tid] += v;
        __syncthreads();
    }
    int run = ps[tid] - v0;
    for (int j = 0; j < per; j++) {
        int i = mybase + j;
        int dgi = sdeg[i];
        scur[i] = beg + run;
        int node = node0 + i;
        if (node < N) row_ptr[node] = beg + run;
        run += dgi;
    }
    if (b == 0 && tid == 0) row_ptr[N] = Etot;
    __syncthreads();
    for (int i = beg + tid; i < end; i += 256) {
        unsigned w = bslab[i];
        int pos = atomicAdd(&scur[w >> 17], 1);  // LDS atomic
        csr_src[pos] = (int)(w & 0x1FFFFu);
    }
}

// ===========================================================================
// xl1 = x @ W1 [N,64] -> packed bf16; as1/ad1 logits. 4 THREADS PER NODE,
// 16 channels (= heads 2q, 2q+1) each -> logit dots stay thread-local.
// Block = 256 thr = 64 nodes; grid 1563 (~16 waves/CU vs 6 before: the old
// 1-thread/node version was occupancy-starved at 13% / 850 GB/s).
// ===========================================================================
__global__ __launch_bounds__(256) void k_gemm1(
    const float* __restrict__ x, const float* __restrict__ W1,
    const float* __restrict__ a_src1, const float* __restrict__ a_dst1,
    unsigned* __restrict__ xl1b, float* __restrict__ as1,
    float* __restrict__ ad1, int N, int F)
{
    __shared__ float Ws[128 * 64];
    __shared__ float asrc[64];
    __shared__ float adst[64];
    for (int i = threadIdx.x; i < F * 64; i += 256) Ws[i] = W1[i];
    if (threadIdx.x < 64) {
        asrc[threadIdx.x] = a_src1[threadIdx.x];
        adst[threadIdx.x] = a_dst1[threadIdx.x];
    }
    __syncthreads();

    int n = blockIdx.x * 64 + (threadIdx.x >> 2);
    int q = threadIdx.x & 3;       // channel quarter: channels 16q..16q+15
    if (n >= N) return;
    int c0 = q * 16;

    float acc[16];
#pragma unroll
    for (int c = 0; c < 16; c++) acc[c] = 0.0f;

    const float4* xr4 = (const float4*)(x + (size_t)n * F);
    for (int k4 = 0; k4 < F / 4; k4++) {
        float4 xv = xr4[k4];
        const float* w0 = &Ws[(k4 * 4 + 0) * 64 + c0];
        const float* w1 = &Ws[(k4 * 4 + 1) * 64 + c0];
        const float* w2 = &Ws[(k4 * 4 + 2) * 64 + c0];
        const float* w3 = &Ws[(k4 * 4 + 3) * 64 + c0];
#pragma unroll
        for (int c = 0; c < 16; c++) {
            float a = acc[c];
            a = fmaf(xv.x, w0[c], a);
            a = fmaf(xv.y, w1[c], a);
            a = fmaf(xv.z, w2[c], a);
            a = fmaf(xv.w, w3[c], a);
            acc[c] = a;
        }
    }

    // Pack 16 channels -> 8 uints (pairs 8q..8q+7), two uint4 stores.
    uint4 pk0, pk1;
    pk0.x = pack_bf16(acc[0], acc[1]);  pk0.y = pack_bf16(acc[2], acc[3]);
    pk0.z = pack_bf16(acc[4], acc[5]);  pk0.w = pack_bf16(acc[6], acc[7]);
    pk1.x = pack_bf16(acc[8], acc[9]);  pk1.y = pack_bf16(acc[10], acc[11]);
    pk1.z = pack_bf16(acc[12], acc[13]); pk1.w = pack_bf16(acc[14], acc[15]);
    uint4* xo = (uint4*)(xl1b + (size_t)n * 32 + q * 8);
    xo[0] = pk0;
    xo[1] = pk1;

    // Heads 2q (channels 0..7 local) and 2q+1 (8..15 local).
#pragma unroll
    for (int hh = 0; hh < 2; hh++) {
        float s = 0.0f, t = 0.0f;
#pragma unroll
        for (int c = 0; c < 8; c++) {
            s = fmaf(acc[hh * 8 + c], asrc[c0 + hh * 8 + c], s);
            t = fmaf(acc[hh * 8 + c], adst[c0 + hh * 8 + c], t);
        }
        as1[(size_t)n * 8 + 2 * q + hh] = s;
        ad1[(size_t)n * 8 + 2 * q + hh] = t;
    }
}

// ===========================================================================
// Layer-1 aggregation (pull), 8-lanes-per-edge layout.
// Wave per dst. lane = 8*g + l: g = edge group (8 edges in flight),
// l = head AND channel-octet (channels 8l..8l+7 via one uint4 = 8 bf16).
// ===========================================================================
__global__ __launch_bounds__(256) void k_agg1(
    const int* __restrict__ row_ptr, const int* __restrict__ csr_src,
    const float* __restrict__ as1, const float* __restrict__ ad1,
    const unsigned* __restrict__ xl1b, const float* __restrict__ b1,
    float* __restrict__ h1, int N)
{
    int d = blockIdx.x * 4 + (threadIdx.x >> 6);
    int lane = threadIdx.x & 63;
    if (d >= N) return;
    int g = lane >> 3;   // edge group
    int l = lane & 7;    // head / channel octet

    int beg = row_ptr[d], end = row_ptr[d + 1];
    float adh = ad1[(size_t)d * 8 + l];

    float ax[8];
#pragma unroll
    for (int j = 0; j < 8; j++) ax[j] = 0.f;
    float den = 0.f;

    for (int i = beg + g; i < end; i += 8) {
        int s = csr_src[i];
        float al = as1[(size_t)s * 8 + l] + adh;
        al = al > 0.f ? al : NEG_SLOPE * al;
        float e = __expf(al);
        uint4 k = *(const uint4*)(xl1b + (size_t)s * 32 + l * 4);
        ax[0] = fmaf(e, bf_lo(k.x), ax[0]);
        ax[1] = fmaf(e, bf_hi(k.x), ax[1]);
        ax[2] = fmaf(e, bf_lo(k.y), ax[2]);
        ax[3] = fmaf(e, bf_hi(k.y), ax[3]);
        ax[4] = fmaf(e, bf_lo(k.z), ax[4]);
        ax[5] = fmaf(e, bf_hi(k.z), ax[5]);
        ax[6] = fmaf(e, bf_lo(k.w), ax[6]);
        ax[7] = fmaf(e, bf_hi(k.w), ax[7]);
        den += e;
    }

#pragma unroll
    for (int m = 8; m < 64; m <<= 1) {
#pragma unroll
        for (int j = 0; j < 8; j++) ax[j] += __shfl_xor(ax[j], m);
        den += __shfl_xor(den, m);
    }

    if (g == 0) {
        float inv = 1.f / (den + GAT_EPS);
        const float4* bb = (const float4*)(b1 + l * 8);
        float4 b0 = bb[0], b1v = bb[1];
        float4 o0, o1;
        float v;
        v = ax[0] * inv + b0.x; o0.x = v > 0.f ? v : expm1f(v);
        v = ax[1] * inv + b0.y; o0.y = v > 0.f ? v : expm1f(v);
        v = ax[2] * inv + b0.z; o0.z = v > 0.f ? v : expm1f(v);
        v = ax[3] * inv + b0.w; o0.w = v > 0.f ? v : expm1f(v);
        v = ax[4] * inv + b1v.x; o1.x = v > 0.f ? v : expm1f(v);
        v = ax[5] * inv + b1v.y; o1.y = v > 0.f ? v : expm1f(v);
        v = ax[6] * inv + b1v.z; o1.z = v > 0.f ? v : expm1f(v);
        v = ax[7] * inv + b1v.w; o1.w = v > 0.f ? v : expm1f(v);
        float4* op = (float4*)(h1 + (size_t)d * 64 + l * 8);
        op[0] = o0;
        op[1] = o1;
    }
}

// ===========================================================================
// Layer-2 node transform: 2 THREADS PER NODE, 20 channels each.
// Block = 256 thr = 128 nodes; grid 782 (~12 waves/CU). Logit dots combined
// with one shfl_xor(1). Packed rows stride 32 uints (pairs 10q..10q+9).
// ===========================================================================
__global__ __launch_bounds__(256) void k_node2(
    const float* __restrict__ h1, const float* __restrict__ W2,
    const float* __restrict__ a_src2, const float* __restrict__ a_dst2,
    unsigned* __restrict__ xl2b, float* __restrict__ as2,
    float* __restrict__ ad2, int N)
{
    __shared__ float Ws[64 * 40];
    __shared__ float a2s[40];
    __shared__ float a2d[40];
    for (int i = threadIdx.x; i < 64 * 40; i += 256) Ws[i] = W2[i];
    if (threadIdx.x < 40) {
        a2s[threadIdx.x] = a_src2[threadIdx.x];
        a2d[threadIdx.x] = a_dst2[threadIdx.x];
    }
    __syncthreads();

    int n = blockIdx.x * 128 + (threadIdx.x >> 1);
    int q = threadIdx.x & 1;      // channel half: channels 20q..20q+19
    if (n >= N) return;
    int c0 = q * 20;

    float o[20];
#pragma unroll
    for (int j = 0; j < 20; j++) o[j] = 0.0f;

    const float4* hr4 = (const float4*)(h1 + (size_t)n * 64);
    for (int k4 = 0; k4 < 16; k4++) {
        float4 hv = hr4[k4];
        const float* w0 = &Ws[(k4 * 4 + 0) * 40 + c0];
        const float* w1 = &Ws[(k4 * 4 + 1) * 40 + c0];
        const float* w2 = &Ws[(k4 * 4 + 2) * 40 + c0];
        const float* w3 = &Ws[(k4 * 4 + 3) * 40 + c0];
#pragma unroll
        for (int j = 0; j < 20; j++) {
            float a = o[j];
            a = fmaf(hv.x, w0[j], a);
            a = fmaf(hv.y, w1[j], a);
            a = fmaf(hv.z, w2[j], a);
            a = fmaf(hv.w, w3[j], a);
            o[j] = a;
        }
    }

    float s = 0.0f, t = 0.0f;
#pragma unroll
    for (int j = 0; j < 20; j++) {
        s = fmaf(o[j], a2s[c0 + j], s);
        t = fmaf(o[j], a2d[c0 + j], t);
    }
    s += __shfl_xor(s, 1);
    t += __shfl_xor(t, 1);
    if (q == 0) { as2[n] = s; ad2[n] = t; }

    unsigned* xo = xl2b + (size_t)n * 32 + q * 10;
#pragma unroll
    for (int p = 0; p < 10; p++) xo[p] = pack_bf16(o[2 * p], o[2 * p + 1]);
}

// ===========================================================================
// Layer-2 aggregation (pull), 8-lanes-per-edge. Only l<5 octets are real
// channels (40 = 5*8); l>=5 read pad (finite garbage) and never store.
// ===========================================================================
__global__ __launch_bounds__(256) void k_agg2(
    const int* __restrict__ row_ptr, const int* __restrict__ csr_src,
    const float* __restrict__ as2, const float* __restrict__ ad2,
    const unsigned* __restrict__ xl2b, const float* __restrict__ b2,
    float* __restrict__ out, int N)
{
    int d = blockIdx.x * 4 + (threadIdx.x >> 6);
    int lane = threadIdx.x & 63;
    if (d >= N) return;
    int g = lane >> 3;
    int l = lane & 7;

    int beg = row_ptr[d], end = row_ptr[d + 1];
    float add = ad2[d];

    float ax[8];
#pragma unroll
    for (int j = 0; j < 8; j++) ax[j] = 0.f;
    float den = 0.f;

    for (int i = beg + g; i < end; i += 8) {
        int s = csr_src[i];
        float al = as2[s] + add;
        al = al > 0.f ? al : NEG_SLOPE * al;
        float e = __expf(al);
        uint4 k = *(const uint4*)(xl2b + (size_t)s * 32 + l * 4);
        ax[0] = fmaf(e, bf_lo(k.x), ax[0]);
        ax[1] = fmaf(e, bf_hi(k.x), ax[1]);
        ax[2] = fmaf(e, bf_lo(k.y), ax[2]);
        ax[3] = fmaf(e, bf_hi(k.y), ax[3]);
        ax[4] = fmaf(e, bf_lo(k.z), ax[4]);
        ax[5] = fmaf(e, bf_hi(k.z), ax[5]);
        ax[6] = fmaf(e, bf_lo(k.w), ax[6]);
        ax[7] = fmaf(e, bf_hi(k.w), ax[7]);
        den += e;
    }

#pragma unroll
    for (int m = 8; m < 64; m <<= 1) {
#pragma unroll
        for (int j = 0; j < 8; j++) ax[j] += __shfl_xor(ax[j], m);
        den += __shfl_xor(den, m);
    }

    if (g == 0 && l < 5) {
        float inv = 1.f / (den + GAT_EPS);
        float* op = out + (size_t)d * 40 + l * 8;
        const float* bb = b2 + l * 8;
#pragma unroll
        for (int j = 0; j < 8; j++) op[j] = ax[j] * inv + bb[j];
    }
}

extern "C" void kernel_launch(void* const* d_in, const int* in_sizes, int n_in,
                              void* d_out, int out_size, void* d_ws, size_t ws_size,
                              hipStream_t stream) {
    const float* x      = (const float*)d_in[0];
    const int*   ei     = (const int*)d_in[1];     // int32 on device
    const float* W1     = (const float*)d_in[2];
    const float* a_src1 = (const float*)d_in[3];
    const float* a_dst1 = (const float*)d_in[4];
    const float* b1     = (const float*)d_in[5];
    const float* W2     = (const float*)d_in[6];
    const float* a_src2 = (const float*)d_in[7];
    const float* a_dst2 = (const float*)d_in[8];
    const float* b2     = (const float*)d_in[9];

    int F = in_sizes[2] / 64;      // 128
    int N = in_sizes[0] / F;       // 100000
    int E = in_sizes[1] / 2;       // 1600000
    int Etot = E + N;
    int NCH = (Etot + CH - 1) / CH;  // 208 chunks
    int shift = 9;                   // 512 nodes/bucket; N<131072 -> <=196 buckets
    while (((N - 1) >> shift) >= NBK) shift++;  // safety (LDS supports shift<=10)

    // Workspace (4-byte words). Peak ~59 MB.
    unsigned* xl1b    = (unsigned*)d_ws;                   // N*32
    float*    h1      = (float*)(xl1b + (size_t)N * 32);   // N*64
    float*    as1     = h1 + (size_t)N * 64;               // N*8
    float*    ad1     = as1 + (size_t)N * 8;               // N*8
    int*      row_ptr = (int*)(ad1 + (size_t)N * 8);       // N+1
    int*      csr_src = row_ptr + (N + 1);                 // Etot
    int*      cnt     = csr_src + Etot;                    // NCH*NBK
    int*      off     = cnt + (size_t)NCH * NBK;           // NCH*NBK
    int*      tot     = off + (size_t)NCH * NBK;           // NBK
    int*      bbase   = tot + NBK;                         // NBK+1
    unsigned* bslab   = (unsigned*)(bbase + NBK + 1);      // Etot
    // Aliases (live only after k_agg1; originals dead by then):
    unsigned* xl2b    = xl1b;                              // N*32 (padded rows)
    float*    as2     = as1;                               // N
    float*    ad2     = ad1;                               // N

    // ---- CSR build: deterministic counting sort, zero global atomics ----
    k_cnt  <<<NCH, 256, 0, stream>>>(ei, E, N, shift, cnt);
    k_off_a<<<NBK, 256, 0, stream>>>(cnt, off, tot, NCH);
    k_off_b<<<1, 256, 0, stream>>>(tot, bbase);
    k_place<<<NCH, 256, 0, stream>>>(ei, E, N, shift, off, bbase, bslab);
    k_csr2 <<<NBK, 256, 0, stream>>>(bbase, bslab, shift,
                                     row_ptr, csr_src, N, Etot);

    // ---- Layer 1 ----
    k_gemm1<<<(N + 63) / 64, 256, 0, stream>>>(x, W1, a_src1, a_dst1,
                                               xl1b, as1, ad1, N, F);
    k_agg1 <<<(N + 3) / 4, 256, 0, stream>>>(row_ptr, csr_src, as1, ad1,
                                             xl1b, b1, h1, N);

    // ---- Layer 2 ----
    k_node2<<<(N + 127) / 128, 256, 0, stream>>>(h1, W2, a_src2, a_dst2,
                                                 xl2b, as2, ad2, N);
    k_agg2 <<<(N + 3) / 4, 256, 0, stream>>>(row_ptr, csr_src, as2, ad2,
                                             xl2b, b2, (float*)d_out, N);
}

// Round 10
// 315.244 us; speedup vs baseline: 1.9480x; 1.0176x over previous
//
#include <hip/hip_runtime.h>
#include <math.h>

#define NEG_SLOPE 0.2f
#define GAT_EPS 1e-16f

#define CH   8192   // edges per chunk (k_cnt / k_place)
#define NBK  256    // coarse buckets; bucket = d >> SHIFT (512 nodes/bucket)
// Pack constraint: s < 2^17 (N <= 131072) and (d & 511) in bits 17..25.

// ---- bf16 pair packing helpers (channel 2p in low half, 2p+1 in high) ----
__device__ __forceinline__ unsigned pack_bf16(float a, float b) {
    unsigned ua = __float_as_uint(a);
    unsigned ub = __float_as_uint(b);
    ua = (ua + 0x8000u) >> 16;
    ub = (ub + 0x8000u) & 0xffff0000u;
    return ua | ub;
}
__device__ __forceinline__ float bf_lo(unsigned pk) {
    return __uint_as_float(pk << 16);
}
__device__ __forceinline__ float bf_hi(unsigned pk) {
    return __uint_as_float(pk & 0xffff0000u);
}

// ===========================================================================
// CSR build via deterministic two-level counting sort — ZERO global atomics.
// Edge ids e >= E are self-loops (s = d = e - E). ei[0..E)=src, ei[E..2E)=dst.
// ===========================================================================

// Pass A: per-chunk LDS histogram over coarse buckets -> cnt[chunk][NBK].
__global__ __launch_bounds__(256) void k_cnt(
    const int* __restrict__ ei, int E, int N, int shift,
    int* __restrict__ cnt)
{
    __shared__ int h[NBK];
    int c = blockIdx.x;
    h[threadIdx.x] = 0;
    __syncthreads();
    int Etot = E + N;
    int base = c * CH;
    int lim = min(base + CH, Etot);
    for (int e = base + threadIdx.x; e < lim; e += 256) {
        int d = (e < E) ? ei[E + e] : (e - E);
        atomicAdd(&h[d >> shift], 1);
    }
    __syncthreads();
    cnt[c * NBK + threadIdx.x] = h[threadIdx.x];
}

// Pass B1: PARALLEL per-bucket scan over chunks (block = bucket).
__global__ __launch_bounds__(256) void k_off_a(
    const int* __restrict__ cnt, int* __restrict__ off,
    int* __restrict__ tot, int NCH)
{
    __shared__ int sm[256];
    int b = blockIdx.x;
    int t = threadIdx.x;
    int carry = 0;
    for (int c0 = 0; c0 < NCH; c0 += 256) {
        int c = c0 + t;
        int v = (c < NCH) ? cnt[c * NBK + b] : 0;
        sm[t] = v;
        __syncthreads();
        for (int o = 1; o < 256; o <<= 1) {
            int add = (t >= o) ? sm[t - o] : 0;
            __syncthreads();
            sm[t] += add;
            __syncthreads();
        }
        if (c < NCH) off[c * NBK + b] = carry + sm[t] - v;  // exclusive
        carry += sm[255];
        __syncthreads();
    }
    if (t == 0) tot[b] = carry;
}

// Pass B2: tiny single-block exclusive scan of bucket totals -> bbase.
__global__ __launch_bounds__(256) void k_off_b(
    const int* __restrict__ tot, int* __restrict__ bbase)
{
    __shared__ int sm[NBK];
    int b = threadIdx.x;
    int v0 = tot[b];
    sm[b] = v0;
    __syncthreads();
    for (int o = 1; o < NBK; o <<= 1) {
        int v = (b >= o) ? sm[b - o] : 0;
        __syncthreads();
        sm[b] += v;
        __syncthreads();
    }
    bbase[b] = sm[b] - v0;
    if (b == NBK - 1) bbase[NBK] = sm[b];
}

// Pass C: re-read chunk edges, rank via LDS cursors (init from bbase+off),
// write packed (s | (d&mask)<<17) into the chunk's exclusive slab ranges.
__global__ __launch_bounds__(256) void k_place(
    const int* __restrict__ ei, int E, int N, int shift,
    const int* __restrict__ off, const int* __restrict__ bbase,
    unsigned* __restrict__ bslab)
{
    __shared__ int cur[NBK];
    int c = blockIdx.x;
    cur[threadIdx.x] = bbase[threadIdx.x] + off[c * NBK + threadIdx.x];
    __syncthreads();
    int Etot = E + N;
    int base = c * CH;
    int lim = min(base + CH, Etot);
    int mask = (1 << shift) - 1;
    for (int e = base + threadIdx.x; e < lim; e += 256) {
        int s, d;
        if (e < E) { s = ei[e]; d = ei[E + e]; }
        else       { s = e - E; d = s; }
        int b = d >> shift;
        int pos = atomicAdd(&cur[b], 1);  // LDS atomic
        bslab[pos] = (unsigned)s | ((unsigned)(d & mask) << 17);
    }
}

// Pass D: block per bucket: LDS fine histogram + scan -> row_ptr, then place
// srcs into the bucket's csr_src window (L2-local). LDS atomics only.
__global__ __launch_bounds__(256) void k_csr2(
    const int* __restrict__ bbase, const unsigned* __restrict__ bslab,
    int shift, int* __restrict__ row_ptr, int* __restrict__ csr_src,
    int N, int Etot)
{
    __shared__ int sdeg[1024];
    __shared__ int scur[1024];
    __shared__ int ps[256];
    int b = blockIdx.x;
    int tid = threadIdx.x;
    int beg = bbase[b], end = bbase[b + 1];
    int nodes = 1 << shift;            // 512 (shift=9); LDS sized for <=1024
    int node0 = b << shift;
    for (int i = tid; i < nodes; i += 256) sdeg[i] = 0;
    __syncthreads();
    for (int i = beg + tid; i < end; i += 256)
        atomicAdd(&sdeg[bslab[i] >> 17], 1);
    __syncthreads();
    int per = (nodes + 255) / 256;
    int mybase = tid * per;
    int sum = 0;
    for (int j = 0; j < per; j++) sum += sdeg[mybase + j];
    ps[tid] = sum;
    __syncthreads();
    int v0 = ps[tid];
    for (int o = 1; o < 256; o <<= 1) {
        int v = (tid >= o) ? ps[tid - o] : 0;
        __syncthreads();
        ps[tid] += v;
        __syncthreads();
    }
    int run = ps[tid] - v0;
    for (int j = 0; j < per; j++) {
        int i = mybase + j;
        int dgi = sdeg[i];
        scur[i] = beg + run;
        int node = node0 + i;
        if (node < N) row_ptr[node] = beg + run;
        run += dgi;
    }
    if (b == 0 && tid == 0) row_ptr[N] = Etot;
    __syncthreads();
    for (int i = beg + tid; i < end; i += 256) {
        unsigned w = bslab[i];
        int pos = atomicAdd(&scur[w >> 17], 1);  // LDS atomic
        csr_src[pos] = (int)(w & 0x1FFFFu);
    }
}

// ===========================================================================
// xl1 = x @ W1 [N,64] -> packed bf16; as1/ad1 logits. 4 THREADS PER NODE,
// 16 channels (= heads 2q, 2q+1) each -> logit dots stay thread-local.
// ===========================================================================
__global__ __launch_bounds__(256) void k_gemm1(
    const float* __restrict__ x, const float* __restrict__ W1,
    const float* __restrict__ a_src1, const float* __restrict__ a_dst1,
    unsigned* __restrict__ xl1b, float* __restrict__ as1,
    float* __restrict__ ad1, int N, int F)
{
    __shared__ float Ws[128 * 64];
    __shared__ float asrc[64];
    __shared__ float adst[64];
    for (int i = threadIdx.x; i < F * 64; i += 256) Ws[i] = W1[i];
    if (threadIdx.x < 64) {
        asrc[threadIdx.x] = a_src1[threadIdx.x];
        adst[threadIdx.x] = a_dst1[threadIdx.x];
    }
    __syncthreads();

    int n = blockIdx.x * 64 + (threadIdx.x >> 2);
    int q = threadIdx.x & 3;       // channel quarter: channels 16q..16q+15
    if (n >= N) return;
    int c0 = q * 16;

    float acc[16];
#pragma unroll
    for (int c = 0; c < 16; c++) acc[c] = 0.0f;

    const float4* xr4 = (const float4*)(x + (size_t)n * F);
    for (int k4 = 0; k4 < F / 4; k4++) {
        float4 xv = xr4[k4];
        const float* w0 = &Ws[(k4 * 4 + 0) * 64 + c0];
        const float* w1 = &Ws[(k4 * 4 + 1) * 64 + c0];
        const float* w2 = &Ws[(k4 * 4 + 2) * 64 + c0];
        const float* w3 = &Ws[(k4 * 4 + 3) * 64 + c0];
#pragma unroll
        for (int c = 0; c < 16; c++) {
            float a = acc[c];
            a = fmaf(xv.x, w0[c], a);
            a = fmaf(xv.y, w1[c], a);
            a = fmaf(xv.z, w2[c], a);
            a = fmaf(xv.w, w3[c], a);
            acc[c] = a;
        }
    }

    uint4 pk0, pk1;
    pk0.x = pack_bf16(acc[0], acc[1]);  pk0.y = pack_bf16(acc[2], acc[3]);
    pk0.z = pack_bf16(acc[4], acc[5]);  pk0.w = pack_bf16(acc[6], acc[7]);
    pk1.x = pack_bf16(acc[8], acc[9]);  pk1.y = pack_bf16(acc[10], acc[11]);
    pk1.z = pack_bf16(acc[12], acc[13]); pk1.w = pack_bf16(acc[14], acc[15]);
    uint4* xo = (uint4*)(xl1b + (size_t)n * 32 + q * 8);
    xo[0] = pk0;
    xo[1] = pk1;

#pragma unroll
    for (int hh = 0; hh < 2; hh++) {
        float s = 0.0f, t = 0.0f;
#pragma unroll
        for (int c = 0; c < 8; c++) {
            s = fmaf(acc[hh * 8 + c], asrc[c0 + hh * 8 + c], s);
            t = fmaf(acc[hh * 8 + c], adst[c0 + hh * 8 + c], t);
        }
        as1[(size_t)n * 8 + 2 * q + hh] = s;
        ad1[(size_t)n * 8 + 2 * q + hh] = t;
    }
}

// ===========================================================================
// Layer-1 aggregation (pull), 8-lanes-per-edge, EDGE LOOP UNROLLED x2:
// each lane handles edges i and i+8 per iteration -> 2 payload gathers +
// 2 csr loads in flight per lane (16 edges/wave-iter), halving the serial
// dependent-chain rounds per dst. Reduction unchanged (3 shfl rounds).
// ===========================================================================
__global__ __launch_bounds__(256) void k_agg1(
    const int* __restrict__ row_ptr, const int* __restrict__ csr_src,
    const float* __restrict__ as1, const float* __restrict__ ad1,
    const unsigned* __restrict__ xl1b, const float* __restrict__ b1,
    float* __restrict__ h1, int N)
{
    int d = blockIdx.x * 4 + (threadIdx.x >> 6);
    int lane = threadIdx.x & 63;
    if (d >= N) return;
    int g = lane >> 3;   // edge group
    int l = lane & 7;    // head / channel octet

    int beg = row_ptr[d], end = row_ptr[d + 1];
    float adh = ad1[(size_t)d * 8 + l];

    float ax[8];
#pragma unroll
    for (int j = 0; j < 8; j++) ax[j] = 0.f;
    float den = 0.f;

    int i = beg + g;
    for (; i + 8 < end; i += 16) {
        int s0 = csr_src[i];
        int s1 = csr_src[i + 8];
        float al0 = as1[(size_t)s0 * 8 + l] + adh;
        float al1 = as1[(size_t)s1 * 8 + l] + adh;
        uint4 k0 = *(const uint4*)(xl1b + (size_t)s0 * 32 + l * 4);
        uint4 k1 = *(const uint4*)(xl1b + (size_t)s1 * 32 + l * 4);
        al0 = al0 > 0.f ? al0 : NEG_SLOPE * al0;
        al1 = al1 > 0.f ? al1 : NEG_SLOPE * al1;
        float e0 = __expf(al0);
        float e1 = __expf(al1);
        ax[0] = fmaf(e0, bf_lo(k0.x), ax[0]);
        ax[1] = fmaf(e0, bf_hi(k0.x), ax[1]);
        ax[2] = fmaf(e0, bf_lo(k0.y), ax[2]);
        ax[3] = fmaf(e0, bf_hi(k0.y), ax[3]);
        ax[4] = fmaf(e0, bf_lo(k0.z), ax[4]);
        ax[5] = fmaf(e0, bf_hi(k0.z), ax[5]);
        ax[6] = fmaf(e0, bf_lo(k0.w), ax[6]);
        ax[7] = fmaf(e0, bf_hi(k0.w), ax[7]);
        ax[0] = fmaf(e1, bf_lo(k1.x), ax[0]);
        ax[1] = fmaf(e1, bf_hi(k1.x), ax[1]);
        ax[2] = fmaf(e1, bf_lo(k1.y), ax[2]);
        ax[3] = fmaf(e1, bf_hi(k1.y), ax[3]);
        ax[4] = fmaf(e1, bf_lo(k1.z), ax[4]);
        ax[5] = fmaf(e1, bf_hi(k1.z), ax[5]);
        ax[6] = fmaf(e1, bf_lo(k1.w), ax[6]);
        ax[7] = fmaf(e1, bf_hi(k1.w), ax[7]);
        den += e0 + e1;
    }
    if (i < end) {
        int s0 = csr_src[i];
        float al0 = as1[(size_t)s0 * 8 + l] + adh;
        uint4 k0 = *(const uint4*)(xl1b + (size_t)s0 * 32 + l * 4);
        al0 = al0 > 0.f ? al0 : NEG_SLOPE * al0;
        float e0 = __expf(al0);
        ax[0] = fmaf(e0, bf_lo(k0.x), ax[0]);
        ax[1] = fmaf(e0, bf_hi(k0.x), ax[1]);
        ax[2] = fmaf(e0, bf_lo(k0.y), ax[2]);
        ax[3] = fmaf(e0, bf_hi(k0.y), ax[3]);
        ax[4] = fmaf(e0, bf_lo(k0.z), ax[4]);
        ax[5] = fmaf(e0, bf_hi(k0.z), ax[5]);
        ax[6] = fmaf(e0, bf_lo(k0.w), ax[6]);
        ax[7] = fmaf(e0, bf_hi(k0.w), ax[7]);
        den += e0;
    }

#pragma unroll
    for (int m = 8; m < 64; m <<= 1) {
#pragma unroll
        for (int j = 0; j < 8; j++) ax[j] += __shfl_xor(ax[j], m);
        den += __shfl_xor(den, m);
    }

    if (g == 0) {
        float inv = 1.f / (den + GAT_EPS);
        const float4* bb = (const float4*)(b1 + l * 8);
        float4 b0 = bb[0], b1v = bb[1];
        float4 o0, o1;
        float v;
        v = ax[0] * inv + b0.x; o0.x = v > 0.f ? v : expm1f(v);
        v = ax[1] * inv + b0.y; o0.y = v > 0.f ? v : expm1f(v);
        v = ax[2] * inv + b0.z; o0.z = v > 0.f ? v : expm1f(v);
        v = ax[3] * inv + b0.w; o0.w = v > 0.f ? v : expm1f(v);
        v = ax[4] * inv + b1v.x; o1.x = v > 0.f ? v : expm1f(v);
        v = ax[5] * inv + b1v.y; o1.y = v > 0.f ? v : expm1f(v);
        v = ax[6] * inv + b1v.z; o1.z = v > 0.f ? v : expm1f(v);
        v = ax[7] * inv + b1v.w; o1.w = v > 0.f ? v : expm1f(v);
        float4* op = (float4*)(h1 + (size_t)d * 64 + l * 8);
        op[0] = o0;
        op[1] = o1;
    }
}

// ===========================================================================
// Layer-2 node transform: 2 THREADS PER NODE, 20 channels each.
// Stores COMPACT bf16 rows: stride 20 uints (80 B, 16B-aligned) — the old
// stride-32 padded rows made agg2 fetch 48B/edge of pad and kept a 12.8MB
// array; compact = 8MB -> better per-XCD L2 fit.
// ===========================================================================
__global__ __launch_bounds__(256) void k_node2(
    const float* __restrict__ h1, const float* __restrict__ W2,
    const float* __restrict__ a_src2, const float* __restrict__ a_dst2,
    unsigned* __restrict__ xl2b, float* __restrict__ as2,
    float* __restrict__ ad2, int N)
{
    __shared__ float Ws[64 * 40];
    __shared__ float a2s[40];
    __shared__ float a2d[40];
    for (int i = threadIdx.x; i < 64 * 40; i += 256) Ws[i] = W2[i];
    if (threadIdx.x < 40) {
        a2s[threadIdx.x] = a_src2[threadIdx.x];
        a2d[threadIdx.x] = a_dst2[threadIdx.x];
    }
    __syncthreads();

    int n = blockIdx.x * 128 + (threadIdx.x >> 1);
    int q = threadIdx.x & 1;      // channel half: channels 20q..20q+19
    if (n >= N) return;
    int c0 = q * 20;

    float o[20];
#pragma unroll
    for (int j = 0; j < 20; j++) o[j] = 0.0f;

    const float4* hr4 = (const float4*)(h1 + (size_t)n * 64);
    for (int k4 = 0; k4 < 16; k4++) {
        float4 hv = hr4[k4];
        const float* w0 = &Ws[(k4 * 4 + 0) * 40 + c0];
        const float* w1 = &Ws[(k4 * 4 + 1) * 40 + c0];
        const float* w2 = &Ws[(k4 * 4 + 2) * 40 + c0];
        const float* w3 = &Ws[(k4 * 4 + 3) * 40 + c0];
#pragma unroll
        for (int j = 0; j < 20; j++) {
            float a = o[j];
            a = fmaf(hv.x, w0[j], a);
            a = fmaf(hv.y, w1[j], a);
            a = fmaf(hv.z, w2[j], a);
            a = fmaf(hv.w, w3[j], a);
            o[j] = a;
        }
    }

    float s = 0.0f, t = 0.0f;
#pragma unroll
    for (int j = 0; j < 20; j++) {
        s = fmaf(o[j], a2s[c0 + j], s);
        t = fmaf(o[j], a2d[c0 + j], t);
    }
    s += __shfl_xor(s, 1);
    t += __shfl_xor(t, 1);
    if (q == 0) { as2[n] = s; ad2[n] = t; }

    unsigned* xo = xl2b + (size_t)n * 20 + q * 10;
#pragma unroll
    for (int p = 0; p < 10; p++) xo[p] = pack_bf16(o[2 * p], o[2 * p + 1]);
}

// ===========================================================================
// Layer-2 aggregation (pull), 8 edges in flight, unrolled x2.
// Compact rows: lane l<5 loads uint4 (uints 4l..4l+3 = channels 8l..8l+7);
// lanes l>=5 are fully predicated off (no loads, no payload VALU) — the
// shfl reduction only mixes same-l columns (strides 8/16/32), so the
// active columns stay clean.
// ===========================================================================
__global__ __launch_bounds__(256) void k_agg2(
    const int* __restrict__ row_ptr, const int* __restrict__ csr_src,
    const float* __restrict__ as2, const float* __restrict__ ad2,
    const unsigned* __restrict__ xl2b, const float* __restrict__ b2,
    float* __restrict__ out, int N)
{
    int d = blockIdx.x * 4 + (threadIdx.x >> 6);
    int lane = threadIdx.x & 63;
    if (d >= N) return;
    int g = lane >> 3;
    int l = lane & 7;
    if (l >= 5) return;   // only 5 octets of 40 channels; reduction is l-local

    int beg = row_ptr[d], end = row_ptr[d + 1];
    float add = ad2[d];

    float ax[8];
#pragma unroll
    for (int j = 0; j < 8; j++) ax[j] = 0.f;
    float den = 0.f;

    int i = beg + g;
    for (; i + 8 < end; i += 16) {
        int s0 = csr_src[i];
        int s1 = csr_src[i + 8];
        float al0 = as2[s0] + add;
        float al1 = as2[s1] + add;
        uint4 k0 = *(const uint4*)(xl2b + (size_t)s0 * 20 + l * 4);
        uint4 k1 = *(const uint4*)(xl2b + (size_t)s1 * 20 + l * 4);
        al0 = al0 > 0.f ? al0 : NEG_SLOPE * al0;
        al1 = al1 > 0.f ? al1 : NEG_SLOPE * al1;
        float e0 = __expf(al0);
        float e1 = __expf(al1);
        ax[0] = fmaf(e0, bf_lo(k0.x), ax[0]);
        ax[1] = fmaf(e0, bf_hi(k0.x), ax[1]);
        ax[2] = fmaf(e0, bf_lo(k0.y), ax[2]);
        ax[3] = fmaf(e0, bf_hi(k0.y), ax[3]);
        ax[4] = fmaf(e0, bf_lo(k0.z), ax[4]);
        ax[5] = fmaf(e0, bf_hi(k0.z), ax[5]);
        ax[6] = fmaf(e0, bf_lo(k0.w), ax[6]);
        ax[7] = fmaf(e0, bf_hi(k0.w), ax[7]);
        ax[0] = fmaf(e1, bf_lo(k1.x), ax[0]);
        ax[1] = fmaf(e1, bf_hi(k1.x), ax[1]);
        ax[2] = fmaf(e1, bf_lo(k1.y), ax[2]);
        ax[3] = fmaf(e1, bf_hi(k1.y), ax[3]);
        ax[4] = fmaf(e1, bf_lo(k1.z), ax[4]);
        ax[5] = fmaf(e1, bf_hi(k1.z), ax[5]);
        ax[6] = fmaf(e1, bf_lo(k1.w), ax[6]);
        ax[7] = fmaf(e1, bf_hi(k1.w), ax[7]);
        den += e0 + e1;
    }
    if (i < end) {
        int s0 = csr_src[i];
        float al0 = as2[s0] + add;
        uint4 k0 = *(const uint4*)(xl2b + (size_t)s0 * 20 + l * 4);
        al0 = al0 > 0.f ? al0 : NEG_SLOPE * al0;
        float e0 = __expf(al0);
        ax[0] = fmaf(e0, bf_lo(k0.x), ax[0]);
        ax[1] = fmaf(e0, bf_hi(k0.x), ax[1]);
        ax[2] = fmaf(e0, bf_lo(k0.y), ax[2]);
        ax[3] = fmaf(e0, bf_hi(k0.y), ax[3]);
        ax[4] = fmaf(e0, bf_lo(k0.z), ax[4]);
        ax[5] = fmaf(e0, bf_hi(k0.z), ax[5]);
        ax[6] = fmaf(e0, bf_lo(k0.w), ax[6]);
        ax[7] = fmaf(e0, bf_hi(k0.w), ax[7]);
        den += e0;
    }

#pragma unroll
    for (int m = 8; m < 64; m <<= 1) {
#pragma unroll
        for (int j = 0; j < 8; j++) ax[j] += __shfl_xor(ax[j], m);
        den += __shfl_xor(den, m);
    }

    if (g == 0) {
        float inv = 1.f / (den + GAT_EPS);
        float* op = out + (size_t)d * 40 + l * 8;
        const float* bb = b2 + l * 8;
#pragma unroll
        for (int j = 0; j < 8; j++) op[j] = ax[j] * inv + bb[j];
    }
}

extern "C" void kernel_launch(void* const* d_in, const int* in_sizes, int n_in,
                              void* d_out, int out_size, void* d_ws, size_t ws_size,
                              hipStream_t stream) {
    const float* x      = (const float*)d_in[0];
    const int*   ei     = (const int*)d_in[1];     // int32 on device
    const float* W1     = (const float*)d_in[2];
    const float* a_src1 = (const float*)d_in[3];
    const float* a_dst1 = (const float*)d_in[4];
    const float* b1     = (const float*)d_in[5];
    const float* W2     = (const float*)d_in[6];
    const float* a_src2 = (const float*)d_in[7];
    const float* a_dst2 = (const float*)d_in[8];
    const float* b2     = (const float*)d_in[9];

    int F = in_sizes[2] / 64;      // 128
    int N = in_sizes[0] / F;       // 100000
    int E = in_sizes[1] / 2;       // 1600000
    int Etot = E + N;
    int NCH = (Etot + CH - 1) / CH;  // 208 chunks
    int shift = 9;                   // 512 nodes/bucket; N<131072 -> <=196 buckets
    while (((N - 1) >> shift) >= NBK) shift++;  // safety (LDS supports shift<=10)

    // Workspace (4-byte words). Peak ~59 MB.
    unsigned* xl1b    = (unsigned*)d_ws;                   // N*32
    float*    h1      = (float*)(xl1b + (size_t)N * 32);   // N*64
    float*    as1     = h1 + (size_t)N * 64;               // N*8
    float*    ad1     = as1 + (size_t)N * 8;               // N*8
    int*      row_ptr = (int*)(ad1 + (size_t)N * 8);       // N+1
    int*      csr_src = row_ptr + (N + 1);                 // Etot
    int*      cnt     = csr_src + Etot;                    // NCH*NBK
    int*      off     = cnt + (size_t)NCH * NBK;           // NCH*NBK
    int*      tot     = off + (size_t)NCH * NBK;           // NBK
    int*      bbase   = tot + NBK;                         // NBK+1
    unsigned* bslab   = (unsigned*)(bbase + NBK + 1);      // Etot
    // Aliases (live only after k_agg1; originals dead by then):
    unsigned* xl2b    = xl1b;                              // N*20 compact rows
    float*    as2     = as1;                               // N
    float*    ad2     = ad1;                               // N

    // ---- CSR build: deterministic counting sort, zero global atomics ----
    k_cnt  <<<NCH, 256, 0, stream>>>(ei, E, N, shift, cnt);
    k_off_a<<<NBK, 256, 0, stream>>>(cnt, off, tot, NCH);
    k_off_b<<<1, 256, 0, stream>>>(tot, bbase);
    k_place<<<NCH, 256, 0, stream>>>(ei, E, N, shift, off, bbase, bslab);
    k_csr2 <<<NBK, 256, 0, stream>>>(bbase, bslab, shift,
                                     row_ptr, csr_src, N, Etot);

    // ---- Layer 1 ----
    k_gemm1<<<(N + 63) / 64, 256, 0, stream>>>(x, W1, a_src1, a_dst1,
                                               xl1b, as1, ad1, N, F);
    k_agg1 <<<(N + 3) / 4, 256, 0, stream>>>(row_ptr, csr_src, as1, ad1,
                                             xl1b, b1, h1, N);

    // ---- Layer 2 ----
    k_node2<<<(N + 127) / 128, 256, 0, stream>>>(h1, W2, a_src2, a_dst2,
                                                 xl2b, as2, ad2, N);
    k_agg2 <<<(N + 3) / 4, 256, 0, stream>>>(row_ptr, csr_src, as2, ad2,
                                             xl2b, b2, (float*)d_out, N);
}